// Round 18
// baseline (777.264 us; speedup 1.0000x reference)
//
#include <hip/hip_runtime.h>

#define EPSF 1e-5f

typedef __attribute__((ext_vector_type(8))) short short8;
typedef __attribute__((ext_vector_type(4))) float f32x4;

__device__ __forceinline__ ushort f2bf(float x) {
    union { float f; unsigned u; } c; c.f = x;
    unsigned r = c.u + 0x7FFF + ((c.u >> 16) & 1);   // RNE
    return (ushort)(r >> 16);
}
__device__ __forceinline__ float bf2f(ushort b) {
    union { unsigned u; float f; } c; c.u = ((unsigned)b) << 16;
    return c.f;
}
// Uniform LDS swizzle: involution on the FULL linear byte address, applied on
// both write and read everywhere (rule #21).
__device__ __forceinline__ int swz(int a) {
    return a ^ (((a >> 7) & 7) << 4);
}

// ---------------------------------------------------------------------------
// Geometry: B=1, C=32, H=96, W=128, L=2, N=7 (49 displacements/level).
// blockIdx.z spans merged (level,d) pairs p = d0 + z, p in [0,98).
// DC capped at 33 so per-chunk intermediates (~195 MB) stay L3-resident.
// Activations NHWC bf16, unpadded:
//   x0s [slot][12288][32] (sampled f2 half)   x1 [slot][12288][96]
//   x2,x3 [slot][3072][128]   x4 [slot][3072][64]  x5 [slot][12288][32]
// P1 [l][bx48][tid512][mf4][nf3][4] f32 = f1 (x) W1[:, 0:32] raw partials.
// F2T [l][12288][32] f32 = f2 transposed to NHWC.
// Weights repacked [l][tap][COUT][CIN] bf16; ctw5 [l][parity][tap][32][64].
// ---------------------------------------------------------------------------

__global__ __launch_bounds__(256) void k_repack_conv(
    const float* __restrict__ src, ushort* __restrict__ dst, int CO, int CI)
{
    int idx = blockIdx.x * 256 + threadIdx.x;
    if (idx >= CO * CI * 9) return;
    int co = idx / (CI * 9);
    int rem = idx % (CI * 9);
    int ci = rem / 9, tap = rem % 9;
    dst[((size_t)tap * CO + co) * CI + ci] = f2bf(src[idx]);
}

// ctw5 [64][32][4][4] fp32 -> [parity(4)][tap(4)][32co][64ci] bf16
__global__ __launch_bounds__(256) void k_repack_ct(
    const float* __restrict__ src, ushort* __restrict__ dst)
{
    int idx = blockIdx.x * 256 + threadIdx.x;
    if (idx >= 4 * 4 * 32 * 64) return;
    int ci = idx & 63;
    int t = idx >> 6;
    int co = t & 31; t >>= 5;
    int tap = t & 3;
    int parity = t >> 2;
    int ph = parity >> 1, pw = parity & 1;
    int a = tap >> 1, b = tap & 1;
    int kh = ((ph + 1) & 1) + 2 * a;
    int kw = ((pw + 1) & 1) + 2 * b;
    dst[idx] = f2bf(src[((ci * 32 + co) * 4 + kh) * 4 + kw]);
}

// ---------------- pack f1 planar fp32 -> xf1 [l][12288][32] bf16 -----------
__global__ __launch_bounds__(256) void k_pack_f1(
    const float* __restrict__ f1_0, const float* __restrict__ f1_1,
    ushort* __restrict__ xf1)
{
    const int sp = blockIdx.x * 256 + threadIdx.x;
    const int l = blockIdx.z;
    const float* f1 = l ? f1_1 : f1_0;
    ushort* dst = xf1 + (size_t)l * 393216 + (size_t)sp * 32;
    #pragma unroll
    for (int g = 0; g < 4; ++g) {
        uint4 pk;
        uint* pw_ = (uint*)&pk;
        #pragma unroll
        for (int q = 0; q < 4; ++q) {
            int c = g * 8 + q * 2;
            pw_[q] = (uint)f2bf(f1[(size_t)c * 12288 + sp])
                   | ((uint)f2bf(f1[(size_t)(c + 1) * 12288 + sp]) << 16);
        }
        *(uint4*)(dst + g * 8) = pk;
    }
}

// ---------------- transpose f2 planar fp32 -> f2t [l][12288][32] f32 -------
__global__ __launch_bounds__(256) void k_transpose_f2(
    const float* __restrict__ f2_0, const float* __restrict__ f2_1,
    float* __restrict__ f2t)
{
    const int sp = blockIdx.x * 256 + threadIdx.x;
    const int l = blockIdx.z;
    const float* f2 = l ? f2_1 : f2_0;
    float* dst = f2t + (size_t)l * 393216 + (size_t)sp * 32;
    #pragma unroll
    for (int c = 0; c < 32; ++c)
        dst[c] = f2[(size_t)c * 12288 + sp];
}

// ---------------- sample f2t (NHWC f32) -> x0s [slot][12288][32] -----------
__global__ __launch_bounds__(256) void k_sample_nhwc(
    const float* __restrict__ f2t, const float* __restrict__ coords,
    ushort* __restrict__ x0s, int d0)
{
    const int HW = 12288;
    const int sp = blockIdx.x * 256 + threadIdx.x;
    const int slot = blockIdx.z;
    const int p = d0 + slot;
    const int l = p / 49;
    const int d = p - l * 49;
    const int du = d / 7, dv = d % 7;
    const float inv_scale = l ? 0.5f : 1.0f;
    const float* ft = f2t + (size_t)l * 393216;

    float cx = coords[sp] * inv_scale + (float)(du - 3);
    float cy = coords[HW + sp] * inv_scale + (float)(dv - 3);
    float xf = floorf(cx), yf = floorf(cy);
    float wx = cx - xf, wy = cy - yf;
    int xi = (int)xf, yi = (int)yf;
    float vx0 = (xf >= 0.f && xf <= 127.f) ? 1.f : 0.f;
    float vx1 = (xf + 1.f >= 0.f && xf + 1.f <= 127.f) ? 1.f : 0.f;
    float vy0 = (yf >= 0.f && yf <= 95.f) ? 1.f : 0.f;
    float vy1 = (yf + 1.f >= 0.f && yf + 1.f <= 95.f) ? 1.f : 0.f;
    int x0i = min(max(xi, 0), 127), x1i = min(max(xi + 1, 0), 127);
    int y0i = min(max(yi, 0), 95),  y1i = min(max(yi + 1, 0), 95);
    float w00 = (1.f - wx) * (1.f - wy) * vx0 * vy0;
    float w01 = wx * (1.f - wy) * vx1 * vy0;
    float w10 = (1.f - wx) * wy * vx0 * vy1;
    float w11 = wx * wy * vx1 * vy1;
    const float* r00 = ft + (size_t)(y0i * 128 + x0i) * 32;
    const float* r01 = ft + (size_t)(y0i * 128 + x1i) * 32;
    const float* r10 = ft + (size_t)(y1i * 128 + x0i) * 32;
    const float* r11 = ft + (size_t)(y1i * 128 + x1i) * 32;

    uint w[16];
    #pragma unroll
    for (int q = 0; q < 8; ++q) {
        float4 a = *(const float4*)(r00 + q * 4);
        float4 b = *(const float4*)(r01 + q * 4);
        float4 c = *(const float4*)(r10 + q * 4);
        float4 e = *(const float4*)(r11 + q * 4);
        float s0 = w00 * a.x + w01 * b.x + w10 * c.x + w11 * e.x;
        float s1 = w00 * a.y + w01 * b.y + w10 * c.y + w11 * e.y;
        float s2 = w00 * a.z + w01 * b.z + w10 * c.z + w11 * e.z;
        float s3 = w00 * a.w + w01 * b.w + w10 * c.w + w11 * e.w;
        w[2 * q]     = (uint)f2bf(s0) | ((uint)f2bf(s1) << 16);
        w[2 * q + 1] = (uint)f2bf(s2) | ((uint)f2bf(s3) << 16);
    }
    ushort* dst = x0s + ((size_t)slot * HW + sp) * 32;
    #pragma unroll
    for (int g = 0; g < 4; ++g)
        *(uint4*)(dst + g * 8) = *(uint4*)(w + g * 4);
}

// ---------------- conv1: merged-co, 8 waves = 4 rows x 2 co-halves ---------
template <int EPI>
__global__ __launch_bounds__(512, 2) void k_conv1(
    const ushort* __restrict__ in,     // EPI0: x0s[slot]; EPI1: xf1[l]
    ushort* __restrict__ out,          // EPI0: x1; EPI1: (float*)P1 base
    const ushort* __restrict__ wbase,  // wr1 [l][9][96][64]
    const float* __restrict__ p1,      // EPI0: P1 base
    const float* __restrict__ bs0, const float* __restrict__ bb0,
    const float* __restrict__ bm0, const float* __restrict__ bv0,
    int d0, int koff)
{
    constexpr int AB = 6 * 66 * 64;              // 25344 B
    constexpr int PB = 3 * 96 * 64;              // 18432 B
    constexpr int SA = 4;
    constexpr int SB = 3;
    __shared__ __align__(16) char smem[AB + 2 * PB];
    char* As = smem;

    const int tid = threadIdx.x;
    const int lane = tid & 63, wid = tid >> 6;
    const int lr = lane & 15, kg = lane >> 4;
    const int bx = blockIdx.x;
    const int rt = bx >> 1, ct = bx & 1;
    const int r0 = rt * 4, c0 = ct * 64;
    const int wr = wid >> 1, coh = wid & 1;
    const int slot = blockIdx.z;
    const int l = EPI ? slot : (d0 + slot) / 49;

    const ushort* ib = in + (size_t)slot * 12288 * 32;
    const ushort* wl = wbase + (size_t)l * (9 * 96 * 64);
    const short8 z8 = {0, 0, 0, 0, 0, 0, 0, 0};

    // ---- A stage (once) ----
    #pragma unroll
    for (int i = 0; i < SA; ++i) {
        int lin = i * 8192 + tid * 16;
        if (lin < AB) {
            int pos = lin >> 6;
            int prow = (pos * 994) >> 16;        // /66 for pos<660
            int pcol = pos - prow * 66;
            int grow = r0 - 1 + prow, gcol = c0 - 1 + pcol;
            bool ok = ((unsigned)grow < 96u) && ((unsigned)gcol < 128u);
            short8 v = z8;
            if (ok) v = *(const short8*)(ib + (grow * 128 + gcol) * 32 + ((lin & 63) >> 1));
            *(short8*)(As + swz(lin)) = v;
        }
    }

    // ---- B staging tables ----
    int boff[SB]; unsigned bmask = 0;
    #pragma unroll
    for (int i = 0; i < SB; ++i) {
        int lin = i * 8192 + tid * 16;
        if (lin < PB) bmask |= 1u << i;
        int lc = min(lin, PB - 16);
        int rowidx = lc >> 6;                    // 0..287
        int tpg = rowidx / 96;                   // kw
        int r = rowidx - tpg * 96;               // co
        boff[i] = (tpg * 96 + r) * 64 + koff + ((lc & 63) >> 1);
    }
    short8 stgB[SB];
    auto loadB = [&](int pg) {
        const ushort* src = wl + pg * (3 * 96 * 64);
        #pragma unroll
        for (int i = 0; i < SB; ++i)
            if ((bmask >> i) & 1) stgB[i] = *(const short8*)(src + boff[i]);
    };
    auto writeB = [&](int pg) {
        char* Bs = smem + AB + (pg & 1) * PB;
        #pragma unroll
        for (int i = 0; i < SB; ++i) {
            int lin = i * 8192 + tid * 16;
            if ((bmask >> i) & 1) *(short8*)(Bs + swz(lin)) = stgB[i];
        }
    };

    // ---- accumulators ----
    f32x4 acc[4][3];
    if constexpr (EPI == 0) {
        const float* pl = p1 + (size_t)l * 1179648
                        + ((size_t)(bx * 512 + tid)) * 48;
        #pragma unroll
        for (int mf = 0; mf < 4; ++mf)
            #pragma unroll
            for (int nf = 0; nf < 3; ++nf)
                acc[mf][nf] = *(const f32x4*)(pl + (mf * 3 + nf) * 4);
    } else {
        #pragma unroll
        for (int mf = 0; mf < 4; ++mf)
            #pragma unroll
            for (int nf = 0; nf < 3; ++nf)
                acc[mf][nf] = (f32x4){0.f, 0.f, 0.f, 0.f};
    }

    loadB(0);
    writeB(0);
    __syncthreads();

    #pragma unroll
    for (int ps = 0; ps < 3; ++ps) {             // ps = kh
        if (ps < 2) loadB(ps + 1);               // T14: issue before compute
        const char* Bs = smem + AB + (ps & 1) * PB;
        #pragma unroll
        for (int kw = 0; kw < 3; ++kw) {
            short8 a[4];
            #pragma unroll
            for (int mf = 0; mf < 4; ++mf) {
                int sp = (wr + ps) * 66 + mf * 16 + lr + kw;
                a[mf] = *(const short8*)(As + swz(sp * 64 + kg * 16));
            }
            #pragma unroll
            for (int nf = 0; nf < 3; ++nf) {
                int rb = kw * 96 + coh * 48 + nf * 16 + lr;
                short8 b = *(const short8*)(Bs + swz(rb * 64 + kg * 16));
                #pragma unroll
                for (int mf = 0; mf < 4; ++mf)
                    acc[mf][nf] = __builtin_amdgcn_mfma_f32_16x16x32_bf16(
                        a[mf], b, acc[mf][nf], 0, 0, 0);
            }
        }
        __syncthreads();
        if (ps < 2) { writeB(ps + 1); __syncthreads(); }
    }

    if constexpr (EPI == 1) {
        float* of = (float*)out + (size_t)l * 1179648
                  + ((size_t)(bx * 512 + tid)) * 48;
        #pragma unroll
        for (int mf = 0; mf < 4; ++mf)
            #pragma unroll
            for (int nf = 0; nf < 3; ++nf)
                *(f32x4*)(of + (mf * 3 + nf) * 4) = acc[mf][nf];
    } else {
        const float* bs = bs0 + l * 96;
        const float* bb = bb0 + l * 96;
        const float* bm = bm0 + l * 96;
        const float* bv = bv0 + l * 96;
        ushort* ob = out + (size_t)slot * 12288 * 96;
        const int orow = r0 + wr;
        #pragma unroll
        for (int nf = 0; nf < 3; ++nf) {
            const int col = coh * 48 + nf * 16 + lr;
            const float inv = bs[col] * rsqrtf(bv[col] + EPSF);
            const float beta = bb[col] - bm[col] * inv;
            #pragma unroll
            for (int mf = 0; mf < 4; ++mf) {
                #pragma unroll
                for (int j = 0; j < 4; ++j) {
                    int ocol = c0 + mf * 16 + kg * 4 + j;
                    float yv = fmaxf(fmaf(acc[mf][nf][j], inv, beta), 0.f);
                    ob[((size_t)orow * 128 + ocol) * 96 + col] = f2bf(yv);
                }
            }
        }
    }
}

// ---------------- conv3: merged-co, async-A (T14), B dbuf ------------------
// x2 [3072][128] -> x3 [3072][128].  blockIdx.x = row-tile (4 rows, full 64
// cols, full 128 co).  8 waves = 4 rows x 2 co-halves; wave = 1 row x 64
// cols x 64 co (acc[4][4]).  A window 6x66 pos x 32ch slice (25.3 KB),
// reg-prefetched at each of CC=4 slice boundaries (issue-early/write-late).
// B page 3kw x 128co x 64B dbuf (24.6 KB x2, T14).  LDS 74.5 KB -> 2/CU.
__global__ __launch_bounds__(512, 2) void k_conv3_mc(
    const ushort* __restrict__ in, ushort* __restrict__ out,
    const ushort* __restrict__ wbase, int wlstride,
    const float* __restrict__ bs0, const float* __restrict__ bb0,
    const float* __restrict__ bm0, const float* __restrict__ bv0, int d0)
{
    constexpr int AB = 6 * 66 * 64;              // 25344 B
    constexpr int PB = 3 * 128 * 64;             // 24576 B
    constexpr int SA = 4;
    constexpr int SB = 3;                        // 3*8192 == PB
    constexpr int NPH = 12;                      // 3 kh x 4 cc
    __shared__ __align__(16) char smem[AB + 2 * PB];
    char* As = smem;

    const int tid = threadIdx.x;
    const int lane = tid & 63, wid = tid >> 6;
    const int lr = lane & 15, kg = lane >> 4;
    const int wr = wid >> 1, coh = wid & 1;
    const int r0 = (int)blockIdx.x * 4;
    const int slot = blockIdx.z;
    const int l = (d0 + slot) / 49;

    int aoff[SA]; unsigned awr = 0, avalid = 0;
    #pragma unroll
    for (int i = 0; i < SA; ++i) {
        int lin = i * 8192 + tid * 16;
        bool wrk = lin < AB;
        int linc = wrk ? lin : 0;
        int pos = linc >> 6;
        int prow = (pos * 994) >> 16;            // /66 for pos<660
        int pcol = pos - prow * 66;
        int grow = r0 - 1 + prow, gcol = pcol - 1;
        bool ok = wrk && ((unsigned)grow < 48u) && ((unsigned)gcol < 64u);
        if (wrk) awr |= 1u << i;
        if (ok) avalid |= 1u << i;
        int growc = min(max(grow, 0), 47), gcolc = min(max(gcol, 0), 63);
        aoff[i] = (growc * 64 + gcolc) * 128 + ((linc & 63) >> 1);
    }
    int boff[SB];
    #pragma unroll
    for (int i = 0; i < SB; ++i) {
        int lin = i * 8192 + tid * 16;           // < PB always
        int rowidx = lin >> 6;                   // 0..383
        int tpg = rowidx >> 7, r = rowidx & 127; // kw, co
        boff[i] = (tpg * 128 + r) * 128 + ((lin & 63) >> 1);
    }

    const ushort* ib = in + (size_t)slot * 3072 * 128;
    const ushort* wl = wbase + (size_t)l * wlstride;
    const short8 z8 = {0, 0, 0, 0, 0, 0, 0, 0};

    short8 stgA[SA], stgB[SB];
    auto loadA = [&](int cc) {
        #pragma unroll
        for (int i = 0; i < SA; ++i) {
            if ((avalid >> i) & 1) stgA[i] = *(const short8*)(ib + aoff[i] + cc * 32);
            else stgA[i] = z8;
        }
    };
    auto writeA = [&]() {
        #pragma unroll
        for (int i = 0; i < SA; ++i) {
            int lin = i * 8192 + tid * 16;
            if ((awr >> i) & 1)
                *(short8*)(As + swz(lin)) = stgA[i];
        }
    };
    auto loadB = [&](int ps) {
        int pg = ps % 3, cc = ps / 3;
        const ushort* src = wl + pg * (3 * 128 * 128) + cc * 32;
        #pragma unroll
        for (int i = 0; i < SB; ++i)
            stgB[i] = *(const short8*)(src + boff[i]);
    };
    auto writeB = [&](int ps) {
        char* Bs = smem + AB + (ps & 1) * PB;
        #pragma unroll
        for (int i = 0; i < SB; ++i) {
            int lin = i * 8192 + tid * 16;
            *(short8*)(Bs + swz(lin)) = stgB[i];
        }
    };

    f32x4 acc[4][4];
    #pragma unroll
    for (int mf = 0; mf < 4; ++mf)
        #pragma unroll
        for (int nf = 0; nf < 4; ++nf)
            acc[mf][nf] = (f32x4){0.f, 0.f, 0.f, 0.f};

    loadA(0); loadB(0);
    writeA(); writeB(0);
    __syncthreads();

    #pragma unroll 1
    for (int ps = 0; ps < NPH; ++ps) {
        const int pg = ps % 3;                    // = kh
        const bool hasNext = (ps + 1 < NPH);
        const bool newA = (pg == 2) && hasNext;
        if (hasNext) loadB(ps + 1);               // T14: issue before compute
        if (newA) loadA(ps / 3 + 1);

        const char* Bs = smem + AB + (ps & 1) * PB;
        #pragma unroll
        for (int kw = 0; kw < 3; ++kw) {
            short8 a[4];
            #pragma unroll
            for (int mf = 0; mf < 4; ++mf) {
                int sp = (wr + pg) * 66 + mf * 16 + lr + kw;
                a[mf] = *(const short8*)(As + swz(sp * 64 + kg * 16));
            }
            #pragma unroll
            for (int nf = 0; nf < 4; ++nf) {
                int rb = kw * 128 + coh * 64 + nf * 16 + lr;
                short8 b = *(const short8*)(Bs + swz(rb * 64 + kg * 16));
                #pragma unroll
                for (int mf = 0; mf < 4; ++mf)
                    acc[mf][nf] = __builtin_amdgcn_mfma_f32_16x16x32_bf16(
                        a[mf], b, acc[mf][nf], 0, 0, 0);
            }
        }

        __syncthreads();
        if (hasNext) {
            writeB(ps + 1);
            if (newA) writeA();
            __syncthreads();
        }
    }

    const float* bs = bs0 + l * 128;
    const float* bb = bb0 + l * 128;
    const float* bm = bm0 + l * 128;
    const float* bv = bv0 + l * 128;
    ushort* ob = out + (size_t)slot * 3072 * 128;
    const int orow = r0 + wr;
    #pragma unroll
    for (int nf = 0; nf < 4; ++nf) {
        const int col = coh * 64 + nf * 16 + lr;
        const float inv = bs[col] * rsqrtf(bv[col] + EPSF);
        const float beta = bb[col] - bm[col] * inv;
        #pragma unroll
        for (int mf = 0; mf < 4; ++mf) {
            #pragma unroll
            for (int j = 0; j < 4; ++j) {
                int ocol = mf * 16 + kg * 4 + j;
                float y = fmaxf(fmaf(acc[mf][nf][j], inv, beta), 0.f);
                ob[((size_t)orow * 64 + ocol) * 128 + col] = f2bf(y);
            }
        }
    }
}

// ---------------- conv4: slim 2-blocks/CU stride-1 conv3x3 -----------------
template <int CIN, int COUT, int IH, int IW>
__global__ __launch_bounds__(512, 4) void k_conv_lds8s(
    const ushort* __restrict__ in, ushort* __restrict__ out,
    const ushort* __restrict__ wbase, int wlstride,
    const float* __restrict__ bs0, const float* __restrict__ bb0,
    const float* __restrict__ bm0, const float* __restrict__ bv0, int d0)
{
    constexpr int CCs = CIN / 32;                // 4
    constexpr int AB = 10 * 66 * 64;             // 42240 B
    constexpr int PB = 3 * 64 * 64;              // 12288 B
    constexpr int SA = 6, SB = 2;
    constexpr int NPH = 3 * CCs;                 // 12
    __shared__ __align__(16) char smem[AB + 2 * PB];
    char* As = smem;

    const int tid = threadIdx.x;
    const int lane = tid & 63, wid = tid >> 6;
    const int lr = lane & 15, kg = lane >> 4;
    const int r0 = (int)blockIdx.x * 8;
    const int co0 = (int)blockIdx.y * 64;
    const int slot = blockIdx.z;
    const int l = (d0 + slot) / 49;

    int aoff[SA]; unsigned awr = 0, avalid = 0;
    #pragma unroll
    for (int i = 0; i < SA; ++i) {
        int lin = i * 8192 + tid * 16;
        bool wr = lin < AB;
        int linc = wr ? lin : 0;
        int pos = linc >> 6;
        int prow = (pos * 994) >> 16;            // /66 for pos<660
        int pcol = pos - prow * 66;
        int grow = r0 - 1 + prow, gcol = pcol - 1;
        bool ok = wr && ((unsigned)grow < (unsigned)IH) && ((unsigned)gcol < (unsigned)IW);
        if (wr) awr |= 1u << i;
        if (ok) avalid |= 1u << i;
        int growc = min(max(grow, 0), IH - 1), gcolc = min(max(gcol, 0), IW - 1);
        aoff[i] = (growc * IW + gcolc) * CIN + ((linc & 63) >> 1);
    }
    int boff[SB]; unsigned bmask = 0;
    #pragma unroll
    for (int i = 0; i < SB; ++i) {
        int lin = i * 8192 + tid * 16;
        if (lin < PB) bmask |= 1u << i;
        int lc = min(lin, PB - 16);
        int rowidx = lc >> 6;                    // 0..191
        int tpg = rowidx >> 6, r = rowidx & 63;  // kw, co offset
        boff[i] = (tpg * COUT + co0 + r) * CIN + ((lc & 63) >> 1);
    }

    const ushort* ib = in + (size_t)slot * IH * IW * CIN;
    const ushort* wl = wbase + (size_t)l * wlstride;
    const short8 z8 = {0, 0, 0, 0, 0, 0, 0, 0};

    auto stageA = [&](int cc) {
        #pragma unroll
        for (int i = 0; i < SA; ++i) {
            int lin = i * 8192 + tid * 16;
            if ((awr >> i) & 1) {
                short8 v = z8;
                if ((avalid >> i) & 1)
                    v = *(const short8*)(ib + aoff[i] + cc * 32);
                *(short8*)(As + swz(lin)) = v;
            }
        }
    };
    short8 stgB[SB];
    auto loadB = [&](int ps) {
        int pg = ps % 3, cc = ps / 3;
        const ushort* src = wl + pg * (3 * COUT * CIN) + cc * 32;
        #pragma unroll
        for (int i = 0; i < SB; ++i)
            if ((bmask >> i) & 1) stgB[i] = *(const short8*)(src + boff[i]);
    };
    auto writeB = [&](int ps) {
        char* Bs = smem + AB + (ps & 1) * PB;
        #pragma unroll
        for (int i = 0; i < SB; ++i) {
            int lin = i * 8192 + tid * 16;
            if ((bmask >> i) & 1) *(short8*)(Bs + swz(lin)) = stgB[i];
        }
    };

    f32x4 acc[4][4];
    #pragma unroll
    for (int mf = 0; mf < 4; ++mf)
        #pragma unroll
        for (int nf = 0; nf < 4; ++nf)
            acc[mf][nf] = (f32x4){0.f, 0.f, 0.f, 0.f};

    stageA(0);
    loadB(0); writeB(0);
    __syncthreads();

    #pragma unroll 1
    for (int ps = 0; ps < NPH; ++ps) {
        const int pg = ps % 3;                    // = kh
        const bool hasNext = (ps + 1 < NPH);
        if (hasNext) loadB(ps + 1);               // T14: issue before compute

        const char* Bs = smem + AB + (ps & 1) * PB;
        #pragma unroll
        for (int kw = 0; kw < 3; ++kw) {
            short8 a[4];
            #pragma unroll
            for (int mf = 0; mf < 4; ++mf) {
                int sp = (wid + pg) * 66 + mf * 16 + lr + kw;
                a[mf] = *(const short8*)(As + swz(sp * 64 + kg * 16));
            }
            #pragma unroll
            for (int nf = 0; nf < 4; ++nf) {
                short8 b = *(const short8*)(Bs + swz((kw * 64 + nf * 16 + lr) * 64 + kg * 16));
                #pragma unroll
                for (int mf = 0; mf < 4; ++mf)
                    acc[mf][nf] = __builtin_amdgcn_mfma_f32_16x16x32_bf16(
                        a[mf], b, acc[mf][nf], 0, 0, 0);
            }
        }

        __syncthreads();
        if (hasNext) {
            writeB(ps + 1);
            if (pg == 2) stageA(ps / 3 + 1);      // synchronous A restage
            __syncthreads();
        }
    }

    const float* bs = bs0 + l * COUT;
    const float* bb = bb0 + l * COUT;
    const float* bm = bm0 + l * COUT;
    const float* bv = bv0 + l * COUT;
    ushort* ob = out + (size_t)slot * IH * IW * COUT;
    const int orow = r0 + wid;
    #pragma unroll
    for (int nf = 0; nf < 4; ++nf) {
        const int col = co0 + nf * 16 + lr;
        const float inv = bs[col] * rsqrtf(bv[col] + EPSF);
        const float beta = bb[col] - bm[col] * inv;
        #pragma unroll
        for (int mf = 0; mf < 4; ++mf) {
            #pragma unroll
            for (int j = 0; j < 4; ++j) {
                int ocol = mf * 16 + kg * 4 + j;
                float y = fmaxf(fmaf(acc[mf][nf][j], inv, beta), 0.f);
                ob[((size_t)orow * IW + ocol) * COUT + col] = f2bf(y);
            }
        }
    }
}

// ---------------- conv2: merged-co, single-buf B, async A (T14) ------------
__global__ __launch_bounds__(512, 2) void k_conv_s2_8(
    const ushort* __restrict__ in, ushort* __restrict__ out,
    const ushort* __restrict__ wbase, int wlstride,
    const float* __restrict__ bs0, const float* __restrict__ bb0,
    const float* __restrict__ bm0, const float* __restrict__ bv0, int d0)
{
    constexpr int AB = 9 * 66 * 64;              // 38016 B
    constexpr int PB = 3 * 128 * 64;             // 24576 B (single buffer)
    constexpr int SA = 5;
    constexpr int SB = 3;                        // 3*8192 == PB exactly
    constexpr int NPH = 9;                       // 3 cc x 3 kh
    __shared__ __align__(16) char smem[AB + PB];
    char* As = smem;

    const int tid = threadIdx.x;
    const int lane = tid & 63, wid = tid >> 6;
    const int lr = lane & 15, kg = lane >> 4;
    const int mw = wid >> 2;                     // 0..1 row-pair
    const int cw = wid & 3;                      // 0..3 co-group of 32
    const int bx = blockIdx.x;
    const int rt = bx >> 1, ct = bx & 1;
    const int r0 = rt * 4, oc0 = ct * 32;
    const int slot = blockIdx.z;
    const int l = (d0 + slot) / 49;

    int aoff[SA]; unsigned awr = 0, avalid = 0;
    #pragma unroll
    for (int i = 0; i < SA; ++i) {
        int lin = i * 8192 + tid * 16;
        bool wr = lin < AB;
        int linc = wr ? lin : 0;
        int pos = linc >> 6;
        int prow = (pos * 994) >> 16;            // /66 for pos<594
        int pcol = pos - prow * 66;
        int grow = 2 * r0 - 1 + prow, gcol = 2 * oc0 - 1 + pcol;
        bool ok = wr && ((unsigned)grow < 96u) && ((unsigned)gcol < 128u);
        if (wr) awr |= 1u << i;
        if (ok) avalid |= 1u << i;
        int growc = min(max(grow, 0), 95), gcolc = min(max(gcol, 0), 127);
        aoff[i] = (growc * 128 + gcolc) * 96 + ((linc & 63) >> 1);
    }
    int boff[SB];
    #pragma unroll
    for (int i = 0; i < SB; ++i) {
        int lin = i * 8192 + tid * 16;           // < PB always
        int rowidx = lin >> 6;                   // 0..383
        int tpg = rowidx >> 7, r = rowidx & 127; // kw, co
        boff[i] = (tpg * 128 + r) * 96 + ((lin & 63) >> 1);
    }

    const ushort* ib = in + (size_t)slot * 12288 * 96;
    const ushort* wl = wbase + (size_t)l * wlstride;
    const short8 z8 = {0, 0, 0, 0, 0, 0, 0, 0};

    short8 stgA[SA], stgB[SB];
    auto loadA = [&](int cc) {
        #pragma unroll
        for (int i = 0; i < SA; ++i) {
            if ((avalid >> i) & 1) stgA[i] = *(const short8*)(ib + aoff[i] + cc * 32);
            else stgA[i] = z8;
        }
    };
    auto writeA = [&]() {
        #pragma unroll
        for (int i = 0; i < SA; ++i) {
            int lin = i * 8192 + tid * 16;
            if ((awr >> i) & 1)
                *(short8*)(As + swz(lin)) = stgA[i];
        }
    };
    auto loadB = [&](int ps) {
        int pg = ps % 3, cc = ps / 3;
        const ushort* src = wl + pg * (3 * 128 * 96) + cc * 32;
        #pragma unroll
        for (int i = 0; i < SB; ++i)
            stgB[i] = *(const short8*)(src + boff[i]);
    };
    auto writeB = [&]() {
        char* Bs = smem + AB;
        #pragma unroll
        for (int i = 0; i < SB; ++i) {
            int lin = i * 8192 + tid * 16;
            *(short8*)(Bs + swz(lin)) = stgB[i];
        }
    };

    f32x4 acc[4][2];
    #pragma unroll
    for (int mf = 0; mf < 4; ++mf)
        #pragma unroll
        for (int nf = 0; nf < 2; ++nf)
            acc[mf][nf] = (f32x4){0.f, 0.f, 0.f, 0.f};

    loadA(0); loadB(0);
    writeA(); writeB();
    __syncthreads();

    #pragma unroll 1
    for (int ps = 0; ps < NPH; ++ps) {
        const int pg = ps % 3;                    // = kh
        const bool hasNext = (ps + 1 < NPH);
        const bool newA = (pg == 2) && hasNext;
        if (hasNext) loadB(ps + 1);               // T14: issue before compute
        if (newA) loadA(ps / 3 + 1);

        const char* Bs = smem + AB;
        #pragma unroll
        for (int kw = 0; kw < 3; ++kw) {
            short8 a[4];
            #pragma unroll
            for (int mf = 0; mf < 4; ++mf) {
                int pos = (2 * (mw * 2 + (mf >> 1)) + pg) * 66
                        + 2 * ((mf & 1) * 16 + lr) + kw;
                a[mf] = *(const short8*)(As + swz(pos * 64 + kg * 16));
            }
            #pragma unroll
            for (int nf = 0; nf < 2; ++nf) {
                int rb = kw * 128 + cw * 32 + nf * 16 + lr;
                short8 b = *(const short8*)(Bs + swz(rb * 64 + kg * 16));
                #pragma unroll
                for (int mf = 0; mf < 4; ++mf)
                    acc[mf][nf] = __builtin_amdgcn_mfma_f32_16x16x32_bf16(
                        a[mf], b, acc[mf][nf], 0, 0, 0);
            }
        }

        __syncthreads();
        if (hasNext) {
            writeB();
            if (newA) writeA();
            __syncthreads();
        }
    }

    const float* bs = bs0 + l * 128;
    const float* bb = bb0 + l * 128;
    const float* bm = bm0 + l * 128;
    const float* bv = bv0 + l * 128;
    ushort* ob = out + (size_t)slot * 3072 * 128;
    #pragma unroll
    for (int nf = 0; nf < 2; ++nf) {
        const int col = cw * 32 + nf * 16 + lr;
        const float inv = bs[col] * rsqrtf(bv[col] + EPSF);
        const float beta = bb[col] - bm[col] * inv;
        #pragma unroll
        for (int mf = 0; mf < 4; ++mf) {
            const int orow = r0 + mw * 2 + (mf >> 1);
            #pragma unroll
            for (int j = 0; j < 4; ++j) {
                int ocol = oc0 + (mf & 1) * 16 + kg * 4 + j;
                float y = fmaxf(fmaf(acc[mf][nf][j], inv, beta), 0.f);
                ob[((size_t)orow * 64 + ocol) * 128 + col] = f2bf(y);
            }
        }
    }
}

// ---------------- convT 4x4 s2: slim LDS, 2 blocks/CU (+BN+ReLU) -----------
__global__ __launch_bounds__(512, 4) void k_convt_lds(
    const ushort* __restrict__ in, ushort* __restrict__ out,
    const ushort* __restrict__ wbase,
    const float* __restrict__ bs0, const float* __restrict__ bb0,
    const float* __restrict__ bm0, const float* __restrict__ bv0, int d0)
{
    constexpr int AB = 10 * 66 * 64;             // 42240 B
    constexpr int PB = 4 * 32 * 64;              // 8192 B
    constexpr int SA = 6;
    __shared__ __align__(16) char smem[AB + 2 * PB];
    char* As = smem;

    const int tid = threadIdx.x;
    const int lane = tid & 63, wid = tid >> 6;
    const int lr = lane & 15, kg = lane >> 4;
    const int q0 = (int)blockIdx.x * 8;
    const int parity = blockIdx.y;
    const int ph = parity >> 1, pw = parity & 1;
    const int slot = blockIdx.z;
    const int l = (d0 + slot) / 49;

    int aoff[SA]; unsigned awr = 0, avalid = 0;
    #pragma unroll
    for (int i = 0; i < SA; ++i) {
        int lin = i * 8192 + tid * 16;
        bool wr = lin < AB;
        int linc = wr ? lin : 0;
        int pos = linc >> 6;
        int prow = (pos * 994) >> 16;            // /66 for pos<660
        int pcol = pos - prow * 66;
        int grow = q0 - 1 + prow, gcol = pcol - 1;
        bool ok = wr && ((unsigned)grow < 48u) && ((unsigned)gcol < 64u);
        if (wr) awr |= 1u << i;
        if (ok) avalid |= 1u << i;
        int growc = min(max(grow, 0), 47), gcolc = min(max(gcol, 0), 63);
        aoff[i] = (growc * 64 + gcolc) * 64 + ((linc & 63) >> 1);
    }
    int boffB;
    {
        int lin = tid * 16;
        int rowidx = lin >> 6;                   // 0..127
        int tap = rowidx >> 5, co = rowidx & 31;
        boffB = ((parity * 4 + tap) * 32 + co) * 64 + ((lin & 63) >> 1);
    }

    const ushort* ib = in + (size_t)slot * 3072 * 64;
    const ushort* wl = wbase + (size_t)l * (16 * 32 * 64);
    const short8 z8 = {0, 0, 0, 0, 0, 0, 0, 0};

    auto stageA = [&](int cc) {
        #pragma unroll
        for (int i = 0; i < SA; ++i) {
            int lin = i * 8192 + tid * 16;
            if ((awr >> i) & 1) {
                short8 v = z8;
                if ((avalid >> i) & 1)
                    v = *(const short8*)(ib + aoff[i] + cc * 32);
                *(short8*)(As + swz(lin)) = v;
            }
        }
    };
    short8 stgB;
    auto loadB = [&](int cc) {
        stgB = *(const short8*)(wl + boffB + cc * 32);
    };
    auto writeB = [&](int cc) {
        char* Bs = smem + AB + (cc & 1) * PB;
        *(short8*)(Bs + swz(tid * 16)) = stgB;
    };

    f32x4 acc[4][2];
    #pragma unroll
    for (int mf = 0; mf < 4; ++mf)
        #pragma unroll
        for (int nf = 0; nf < 2; ++nf)
            acc[mf][nf] = (f32x4){0.f, 0.f, 0.f, 0.f};

    stageA(0);
    loadB(0); writeB(0);
    __syncthreads();

    #pragma unroll 1
    for (int cc = 0; cc < 2; ++cc) {
        if (cc == 0) loadB(1);                   // T14: issue before compute
        const char* Bs = smem + AB + (cc & 1) * PB;
        #pragma unroll
        for (int a = 0; a < 2; ++a) {
            #pragma unroll
            for (int b2 = 0; b2 < 2; ++b2) {
                const int tap = a * 2 + b2;
                short8 av[4];
                #pragma unroll
                for (int mf = 0; mf < 4; ++mf) {
                    int pos = (wid + 1 + ph - a) * 66 + mf * 16 + lr + pw - b2 + 1;
                    av[mf] = *(const short8*)(As + swz(pos * 64 + kg * 16));
                }
                #pragma unroll
                for (int nf = 0; nf < 2; ++nf) {
                    short8 b = *(const short8*)(Bs
                        + swz((tap * 32 + nf * 16 + lr) * 64 + kg * 16));
                    #pragma unroll
                    for (int mf = 0; mf < 4; ++mf)
                        acc[mf][nf] = __builtin_amdgcn_mfma_f32_16x16x32_bf16(
                            av[mf], b, acc[mf][nf], 0, 0, 0);
                }
            }
        }
        __syncthreads();
        if (cc == 0) {
            writeB(1);
            stageA(1);                            // synchronous A restage
            __syncthreads();
        }
    }

    const float* bs = bs0 + l * 32;
    const float* bb = bb0 + l * 32;
    const float* bm = bm0 + l * 32;
    const float* bv = bv0 + l * 32;
    ushort* ob = out + (size_t)slot * 12288 * 32;
    const size_t rowb = (size_t)(2 * (q0 + wid) + ph) * 128;
    #pragma unroll
    for (int nf = 0; nf < 2; ++nf) {
        const int col = nf * 16 + lr;
        const float inv = bs[col] * rsqrtf(bv[col] + EPSF);
        const float beta = bb[col] - bm[col] * inv;
        #pragma unroll
        for (int mf = 0; mf < 4; ++mf) {
            #pragma unroll
            for (int j = 0; j < 4; ++j) {
                int r = mf * 16 + kg * 4 + j;
                float y = fmaxf(fmaf(acc[mf][nf][j], inv, beta), 0.f);
                ob[(rowb + 2 * r + pw) * 32 + col] = f2bf(y);
            }
        }
    }
}

// ---------------- conv6 (32->1) + bias, fp32 out ---------------------------
__global__ __launch_bounds__(256) void k_conv6(
    const ushort* __restrict__ x5, float* __restrict__ cost,
    const float* __restrict__ w0, const float* __restrict__ cb6, int d0)
{
    const int sp = blockIdx.x * 256 + threadIdx.x;
    const int slot = blockIdx.z;
    const int p = d0 + slot;
    const int l = p / 49;
    const float* w = w0 + l * 288;
    const int oh = sp >> 7, ow = sp & 127;
    float acc = 0.f;
    #pragma unroll
    for (int kh = 0; kh < 3; ++kh) {
        const int ih = oh - 1 + kh;
        if (ih < 0 || ih >= 96) continue;
        #pragma unroll
        for (int kw = 0; kw < 3; ++kw) {
            const int iw = ow - 1 + kw;
            if (iw < 0 || iw >= 128) continue;
            const ushort* q = x5 + ((size_t)slot * 12288 + ih * 128 + iw) * 32;
            const int tap = kh * 3 + kw;
            #pragma unroll
            for (int g = 0; g < 4; ++g) {
                uint4 v = *(const uint4*)(q + g * 8);
                const uint* vw = (const uint*)&v;
                #pragma unroll
                for (int t = 0; t < 4; ++t) {
                    int ci = g * 8 + t * 2;
                    acc = fmaf(bf2f((ushort)(vw[t] & 0xFFFF)), w[ci * 9 + tap], acc);
                    acc = fmaf(bf2f((ushort)(vw[t] >> 16)), w[(ci + 1) * 9 + tap], acc);
                }
            }
        }
    }
    cost[(size_t)p * 12288 + sp] = acc + cb6[l];
}

// ---------------- DAP ------------------------------------------------------
__global__ __launch_bounds__(256) void k_dap(
    const float* __restrict__ cost, const float* __restrict__ dw,
    float* __restrict__ out)
{
    const int sp = blockIdx.x * 256 + threadIdx.x;
    const int p = blockIdx.y;
    const float* dr = dw + p * 49;
    float acc = 0.f;
    #pragma unroll
    for (int q = 0; q < 49; ++q)
        acc = fmaf(dr[q], cost[(size_t)q * 12288 + sp], acc);
    out[(size_t)p * 12288 + sp] = acc;
}

// ---------------------------------------------------------------------------
extern "C" void kernel_launch(void* const* d_in, const int* in_sizes, int n_in,
                              void* d_out, int out_size, void* d_ws, size_t ws_size,
                              hipStream_t stream)
{
    const float* fm1_0 = (const float*)d_in[0];
    const float* fm2_0 = (const float*)d_in[1];
    const float* fm1_1 = (const float*)d_in[2];
    const float* fm2_1 = (const float*)d_in[3];
    const float* coords = (const float*)d_in[4];
    const float* cw1  = (const float*)d_in[5];
    const float* cw2  = (const float*)d_in[6];
    const float* cw3  = (const float*)d_in[7];
    const float* cw4  = (const float*)d_in[8];
    const float* ctw5 = (const float*)d_in[9];
    const float* cw6  = (const float*)d_in[10];
    const float* cb6  = (const float*)d_in[11];
    const float* bn[5][4];
    for (int j = 0; j < 5; ++j)
        for (int k = 0; k < 4; ++k)
            bn[j][k] = (const float*)d_in[12 + j * 4 + k];
    const float* dap = (const float*)d_in[32];
    float* out = (float*)d_out;

    // ---- workspace: bufA | bufB | xf1(2 lv) | weights | P1 | cost | f2t ----
    const size_t A_US = 393216;    // per-slot: max(x0s, x2, x4)
    const size_t B_US = 1179648;   // per-slot: max(x1, x3, x5)
    const size_t XF1 = 2 * 393216;
    const size_t W1 = 9 * 96 * 64, W2 = 9 * 128 * 96, W3 = 9 * 128 * 128;
    const size_t W4 = 9 * 64 * 128, W5 = 16 * 32 * 64;
    const size_t W_US = 2 * (W1 + W2 + W3 + W4 + W5);
    const size_t P1F = 2 * (size_t)48 * 512 * 48;      // floats, both levels
    const size_t COSTF = (size_t)98 * 12288;
    const size_t F2TF = 2 * (size_t)12288 * 32;        // floats, both levels

    int DC = 1;
    for (int cand : {98, 66, 49, 42, 33, 25, 17, 13, 9, 7, 5, 3, 2, 1}) {
        size_t need = (A_US + B_US) * (size_t)cand * 2 + (XF1 + W_US) * 2
                    + (P1F + COSTF + F2TF) * 4 + 4096;
        if (need <= ws_size) { DC = cand; break; }
    }
    if (DC > 33) DC = 33;   // keep per-chunk intermediates L3-resident

    ushort* bufA = (ushort*)d_ws;
    ushort* bufB = bufA + A_US * DC;
    ushort* xf1 = bufB + B_US * DC;
    ushort* wp = xf1 + XF1;
    ushort* wr1 = wp; wp += 2 * W1;
    ushort* wr2 = wp; wp += 2 * W2;
    ushort* wr3 = wp; wp += 2 * W3;
    ushort* wr4 = wp; wp += 2 * W4;
    ushort* wr5 = wp; wp += 2 * W5;
    float* P1 = (float*)wp;
    float* cost = P1 + P1F;
    float* f2t = cost + COSTF;

    for (int l = 0; l < 2; ++l) {
        k_repack_conv<<<dim3(216), 256, 0, stream>>>(cw1 + (size_t)l * W1, wr1 + l * W1, 96, 64);
        k_repack_conv<<<dim3(432), 256, 0, stream>>>(cw2 + (size_t)l * W2, wr2 + l * W2, 128, 96);
        k_repack_conv<<<dim3(576), 256, 0, stream>>>(cw3 + (size_t)l * W3, wr3 + l * W3, 128, 128);
        k_repack_conv<<<dim3(288), 256, 0, stream>>>(cw4 + (size_t)l * W4, wr4 + l * W4, 64, 128);
        k_repack_ct<<<dim3(128), 256, 0, stream>>>(ctw5 + (size_t)l * W5, wr5 + l * W5);
    }

    // ---- one-time: f2 NHWC transpose + P1 = f1 (x) W1[:, 0:32] ----
    k_transpose_f2<<<dim3(48, 1, 2), 256, 0, stream>>>(fm2_0, fm2_1, f2t);
    k_pack_f1<<<dim3(48, 1, 2), 256, 0, stream>>>(fm1_0, fm1_1, xf1);
    k_conv1<1><<<dim3(48, 1, 2), 512, 0, stream>>>(
        xf1, (ushort*)P1, wr1, nullptr,
        bn[0][0], bn[0][1], bn[0][2], bn[0][3], 0, 0);

    for (int d0 = 0; d0 < 98; d0 += DC) {
        const int ndd = min(DC, 98 - d0);
        k_sample_nhwc<<<dim3(48, 1, ndd), 256, 0, stream>>>(
            f2t, coords, bufA, d0);
        k_conv1<0><<<dim3(48, 1, ndd), 512, 0, stream>>>(
            bufA, bufB, wr1, P1,
            bn[0][0], bn[0][1], bn[0][2], bn[0][3], d0, 32);
        k_conv_s2_8<<<dim3(24, 1, ndd), 512, 0, stream>>>(bufB, bufA, wr2, (int)W2,
                bn[1][0], bn[1][1], bn[1][2], bn[1][3], d0);
        k_conv3_mc<<<dim3(12, 1, ndd), 512, 0, stream>>>(bufA, bufB, wr3, (int)W3,
                bn[2][0], bn[2][1], bn[2][2], bn[2][3], d0);
        k_conv_lds8s<128, 64, 48, 64>
            <<<dim3(6, 1, ndd), 512, 0, stream>>>(bufB, bufA, wr4, (int)W4,
                bn[3][0], bn[3][1], bn[3][2], bn[3][3], d0);
        k_convt_lds<<<dim3(6, 4, ndd), 512, 0, stream>>>(bufA, bufB, wr5,
                bn[4][0], bn[4][1], bn[4][2], bn[4][3], d0);
        k_conv6<<<dim3(48, 1, ndd), 256, 0, stream>>>(
            bufB, cost, cw6, cb6, d0);
    }
    for (int l = 0; l < 2; ++l)
        k_dap<<<dim3(48, 49), 256, 0, stream>>>(
            cost + (size_t)l * 49 * 12288, dap + (size_t)l * 49 * 49,
            out + (size_t)l * 49 * 12288);
}

// Round 19
// 717.504 us; speedup vs baseline: 1.0833x; 1.0833x over previous
//
#include <hip/hip_runtime.h>

#define EPSF 1e-5f

typedef __attribute__((ext_vector_type(8))) short short8;
typedef __attribute__((ext_vector_type(4))) float f32x4;

__device__ __forceinline__ ushort f2bf(float x) {
    union { float f; unsigned u; } c; c.f = x;
    unsigned r = c.u + 0x7FFF + ((c.u >> 16) & 1);   // RNE
    return (ushort)(r >> 16);
}
__device__ __forceinline__ float bf2f(ushort b) {
    union { unsigned u; float f; } c; c.u = ((unsigned)b) << 16;
    return c.f;
}
// Uniform LDS swizzle: involution on the FULL linear byte address, applied on
// both write and read everywhere (rule #21).
__device__ __forceinline__ int swz(int a) {
    return a ^ (((a >> 7) & 7) << 4);
}

// ---------------------------------------------------------------------------
// Geometry: B=1, C=32, H=96, W=128, L=2, N=7 (49 displacements/level).
// blockIdx.z spans merged (level,d) pairs p = d0 + z, p in [0,98).
// Activations NHWC bf16, unpadded:
//   x0s [slot][12288][32] (sampled f2 half)   x1 [slot][12288][96]
//   x2,x3 [slot][3072][128]   x4 [slot][3072][64]  x5 [slot][12288][32]
// P1 [l][bx48][tid512][mf4][nf3][4] f32 = f1 (x) W1[:, 0:32] raw partials.
// F2T [l][12288][32] f32 = f2 transposed to NHWC.
// Weights repacked [l][tap][COUT][CIN] bf16; ctw5 [l][parity][tap][32][64].
// ---------------------------------------------------------------------------

__global__ __launch_bounds__(256) void k_repack_conv(
    const float* __restrict__ src, ushort* __restrict__ dst, int CO, int CI)
{
    int idx = blockIdx.x * 256 + threadIdx.x;
    if (idx >= CO * CI * 9) return;
    int co = idx / (CI * 9);
    int rem = idx % (CI * 9);
    int ci = rem / 9, tap = rem % 9;
    dst[((size_t)tap * CO + co) * CI + ci] = f2bf(src[idx]);
}

// ctw5 [64][32][4][4] fp32 -> [parity(4)][tap(4)][32co][64ci] bf16
__global__ __launch_bounds__(256) void k_repack_ct(
    const float* __restrict__ src, ushort* __restrict__ dst)
{
    int idx = blockIdx.x * 256 + threadIdx.x;
    if (idx >= 4 * 4 * 32 * 64) return;
    int ci = idx & 63;
    int t = idx >> 6;
    int co = t & 31; t >>= 5;
    int tap = t & 3;
    int parity = t >> 2;
    int ph = parity >> 1, pw = parity & 1;
    int a = tap >> 1, b = tap & 1;
    int kh = ((ph + 1) & 1) + 2 * a;
    int kw = ((pw + 1) & 1) + 2 * b;
    dst[idx] = f2bf(src[((ci * 32 + co) * 4 + kh) * 4 + kw]);
}

// ---------------- pack f1 planar fp32 -> xf1 [l][12288][32] bf16 -----------
__global__ __launch_bounds__(256) void k_pack_f1(
    const float* __restrict__ f1_0, const float* __restrict__ f1_1,
    ushort* __restrict__ xf1)
{
    const int sp = blockIdx.x * 256 + threadIdx.x;
    const int l = blockIdx.z;
    const float* f1 = l ? f1_1 : f1_0;
    ushort* dst = xf1 + (size_t)l * 393216 + (size_t)sp * 32;
    #pragma unroll
    for (int g = 0; g < 4; ++g) {
        uint4 pk;
        uint* pw_ = (uint*)&pk;
        #pragma unroll
        for (int q = 0; q < 4; ++q) {
            int c = g * 8 + q * 2;
            pw_[q] = (uint)f2bf(f1[(size_t)c * 12288 + sp])
                   | ((uint)f2bf(f1[(size_t)(c + 1) * 12288 + sp]) << 16);
        }
        *(uint4*)(dst + g * 8) = pk;
    }
}

// ---------------- transpose f2 planar fp32 -> f2t [l][12288][32] f32 -------
__global__ __launch_bounds__(256) void k_transpose_f2(
    const float* __restrict__ f2_0, const float* __restrict__ f2_1,
    float* __restrict__ f2t)
{
    const int sp = blockIdx.x * 256 + threadIdx.x;
    const int l = blockIdx.z;
    const float* f2 = l ? f2_1 : f2_0;
    float* dst = f2t + (size_t)l * 393216 + (size_t)sp * 32;
    #pragma unroll
    for (int c = 0; c < 32; ++c)
        dst[c] = f2[(size_t)c * 12288 + sp];
}

// ---------------- sample f2t (NHWC f32) -> x0s [slot][12288][32] -----------
__global__ __launch_bounds__(256) void k_sample_nhwc(
    const float* __restrict__ f2t, const float* __restrict__ coords,
    ushort* __restrict__ x0s, int d0)
{
    const int HW = 12288;
    const int sp = blockIdx.x * 256 + threadIdx.x;
    const int slot = blockIdx.z;
    const int p = d0 + slot;
    const int l = p / 49;
    const int d = p - l * 49;
    const int du = d / 7, dv = d % 7;
    const float inv_scale = l ? 0.5f : 1.0f;
    const float* ft = f2t + (size_t)l * 393216;

    float cx = coords[sp] * inv_scale + (float)(du - 3);
    float cy = coords[HW + sp] * inv_scale + (float)(dv - 3);
    float xf = floorf(cx), yf = floorf(cy);
    float wx = cx - xf, wy = cy - yf;
    int xi = (int)xf, yi = (int)yf;
    float vx0 = (xf >= 0.f && xf <= 127.f) ? 1.f : 0.f;
    float vx1 = (xf + 1.f >= 0.f && xf + 1.f <= 127.f) ? 1.f : 0.f;
    float vy0 = (yf >= 0.f && yf <= 95.f) ? 1.f : 0.f;
    float vy1 = (yf + 1.f >= 0.f && yf + 1.f <= 95.f) ? 1.f : 0.f;
    int x0i = min(max(xi, 0), 127), x1i = min(max(xi + 1, 0), 127);
    int y0i = min(max(yi, 0), 95),  y1i = min(max(yi + 1, 0), 95);
    float w00 = (1.f - wx) * (1.f - wy) * vx0 * vy0;
    float w01 = wx * (1.f - wy) * vx1 * vy0;
    float w10 = (1.f - wx) * wy * vx0 * vy1;
    float w11 = wx * wy * vx1 * vy1;
    const float* r00 = ft + (size_t)(y0i * 128 + x0i) * 32;
    const float* r01 = ft + (size_t)(y0i * 128 + x1i) * 32;
    const float* r10 = ft + (size_t)(y1i * 128 + x0i) * 32;
    const float* r11 = ft + (size_t)(y1i * 128 + x1i) * 32;

    uint w[16];
    #pragma unroll
    for (int q = 0; q < 8; ++q) {
        float4 a = *(const float4*)(r00 + q * 4);
        float4 b = *(const float4*)(r01 + q * 4);
        float4 c = *(const float4*)(r10 + q * 4);
        float4 e = *(const float4*)(r11 + q * 4);
        float s0 = w00 * a.x + w01 * b.x + w10 * c.x + w11 * e.x;
        float s1 = w00 * a.y + w01 * b.y + w10 * c.y + w11 * e.y;
        float s2 = w00 * a.z + w01 * b.z + w10 * c.z + w11 * e.z;
        float s3 = w00 * a.w + w01 * b.w + w10 * c.w + w11 * e.w;
        w[2 * q]     = (uint)f2bf(s0) | ((uint)f2bf(s1) << 16);
        w[2 * q + 1] = (uint)f2bf(s2) | ((uint)f2bf(s3) << 16);
    }
    ushort* dst = x0s + ((size_t)slot * HW + sp) * 32;
    #pragma unroll
    for (int g = 0; g < 4; ++g)
        *(uint4*)(dst + g * 8) = *(uint4*)(w + g * 4);
}

// ---------------- conv1: merged-co, 8 waves = 4 rows x 2 co-halves ---------
template <int EPI>
__global__ __launch_bounds__(512, 2) void k_conv1(
    const ushort* __restrict__ in,     // EPI0: x0s[slot]; EPI1: xf1[l]
    ushort* __restrict__ out,          // EPI0: x1; EPI1: (float*)P1 base
    const ushort* __restrict__ wbase,  // wr1 [l][9][96][64]
    const float* __restrict__ p1,      // EPI0: P1 base
    const float* __restrict__ bs0, const float* __restrict__ bb0,
    const float* __restrict__ bm0, const float* __restrict__ bv0,
    int d0, int koff)
{
    constexpr int AB = 6 * 66 * 64;              // 25344 B
    constexpr int PB = 3 * 96 * 64;              // 18432 B
    constexpr int SA = 4;
    constexpr int SB = 3;
    __shared__ __align__(16) char smem[AB + 2 * PB];
    char* As = smem;

    const int tid = threadIdx.x;
    const int lane = tid & 63, wid = tid >> 6;
    const int lr = lane & 15, kg = lane >> 4;
    const int bx = blockIdx.x;
    const int rt = bx >> 1, ct = bx & 1;
    const int r0 = rt * 4, c0 = ct * 64;
    const int wr = wid >> 1, coh = wid & 1;
    const int slot = blockIdx.z;
    const int l = EPI ? slot : (d0 + slot) / 49;

    const ushort* ib = in + (size_t)slot * 12288 * 32;
    const ushort* wl = wbase + (size_t)l * (9 * 96 * 64);
    const short8 z8 = {0, 0, 0, 0, 0, 0, 0, 0};

    // ---- A stage (once) ----
    #pragma unroll
    for (int i = 0; i < SA; ++i) {
        int lin = i * 8192 + tid * 16;
        if (lin < AB) {
            int pos = lin >> 6;
            int prow = (pos * 994) >> 16;        // /66 for pos<660
            int pcol = pos - prow * 66;
            int grow = r0 - 1 + prow, gcol = c0 - 1 + pcol;
            bool ok = ((unsigned)grow < 96u) && ((unsigned)gcol < 128u);
            short8 v = z8;
            if (ok) v = *(const short8*)(ib + (grow * 128 + gcol) * 32 + ((lin & 63) >> 1));
            *(short8*)(As + swz(lin)) = v;
        }
    }

    // ---- B staging tables ----
    int boff[SB]; unsigned bmask = 0;
    #pragma unroll
    for (int i = 0; i < SB; ++i) {
        int lin = i * 8192 + tid * 16;
        if (lin < PB) bmask |= 1u << i;
        int lc = min(lin, PB - 16);
        int rowidx = lc >> 6;                    // 0..287
        int tpg = rowidx / 96;                   // kw
        int r = rowidx - tpg * 96;               // co
        boff[i] = (tpg * 96 + r) * 64 + koff + ((lc & 63) >> 1);
    }
    short8 stgB[SB];
    auto loadB = [&](int pg) {
        const ushort* src = wl + pg * (3 * 96 * 64);
        #pragma unroll
        for (int i = 0; i < SB; ++i)
            if ((bmask >> i) & 1) stgB[i] = *(const short8*)(src + boff[i]);
    };
    auto writeB = [&](int pg) {
        char* Bs = smem + AB + (pg & 1) * PB;
        #pragma unroll
        for (int i = 0; i < SB; ++i) {
            int lin = i * 8192 + tid * 16;
            if ((bmask >> i) & 1) *(short8*)(Bs + swz(lin)) = stgB[i];
        }
    };

    // ---- accumulators ----
    f32x4 acc[4][3];
    if constexpr (EPI == 0) {
        const float* pl = p1 + (size_t)l * 1179648
                        + ((size_t)(bx * 512 + tid)) * 48;
        #pragma unroll
        for (int mf = 0; mf < 4; ++mf)
            #pragma unroll
            for (int nf = 0; nf < 3; ++nf)
                acc[mf][nf] = *(const f32x4*)(pl + (mf * 3 + nf) * 4);
    } else {
        #pragma unroll
        for (int mf = 0; mf < 4; ++mf)
            #pragma unroll
            for (int nf = 0; nf < 3; ++nf)
                acc[mf][nf] = (f32x4){0.f, 0.f, 0.f, 0.f};
    }

    loadB(0);
    writeB(0);
    __syncthreads();

    #pragma unroll
    for (int ps = 0; ps < 3; ++ps) {             // ps = kh
        if (ps < 2) loadB(ps + 1);               // T14: issue before compute
        const char* Bs = smem + AB + (ps & 1) * PB;
        #pragma unroll
        for (int kw = 0; kw < 3; ++kw) {
            short8 a[4];
            #pragma unroll
            for (int mf = 0; mf < 4; ++mf) {
                int sp = (wr + ps) * 66 + mf * 16 + lr + kw;
                a[mf] = *(const short8*)(As + swz(sp * 64 + kg * 16));
            }
            #pragma unroll
            for (int nf = 0; nf < 3; ++nf) {
                int rb = kw * 96 + coh * 48 + nf * 16 + lr;
                short8 b = *(const short8*)(Bs + swz(rb * 64 + kg * 16));
                #pragma unroll
                for (int mf = 0; mf < 4; ++mf)
                    acc[mf][nf] = __builtin_amdgcn_mfma_f32_16x16x32_bf16(
                        a[mf], b, acc[mf][nf], 0, 0, 0);
            }
        }
        __syncthreads();
        if (ps < 2) { writeB(ps + 1); __syncthreads(); }
    }

    if constexpr (EPI == 1) {
        float* of = (float*)out + (size_t)l * 1179648
                  + ((size_t)(bx * 512 + tid)) * 48;
        #pragma unroll
        for (int mf = 0; mf < 4; ++mf)
            #pragma unroll
            for (int nf = 0; nf < 3; ++nf)
                *(f32x4*)(of + (mf * 3 + nf) * 4) = acc[mf][nf];
    } else {
        const float* bs = bs0 + l * 96;
        const float* bb = bb0 + l * 96;
        const float* bm = bm0 + l * 96;
        const float* bv = bv0 + l * 96;
        ushort* ob = out + (size_t)slot * 12288 * 96;
        const int orow = r0 + wr;
        #pragma unroll
        for (int nf = 0; nf < 3; ++nf) {
            const int col = coh * 48 + nf * 16 + lr;
            const float inv = bs[col] * rsqrtf(bv[col] + EPSF);
            const float beta = bb[col] - bm[col] * inv;
            #pragma unroll
            for (int mf = 0; mf < 4; ++mf) {
                #pragma unroll
                for (int j = 0; j < 4; ++j) {
                    int ocol = c0 + mf * 16 + kg * 4 + j;
                    float yv = fmaxf(fmaf(acc[mf][nf][j], inv, beta), 0.f);
                    ob[((size_t)orow * 128 + ocol) * 96 + col] = f2bf(yv);
                }
            }
        }
    }
}

// ---------------- conv3: merged-co, async-A (T14), B dbuf ------------------
// x2 [3072][128] -> x3 [3072][128].  blockIdx.x = row-tile (4 rows, full 64
// cols, full 128 co).  8 waves = 4 rows x 2 co-halves; wave = 1 row x 64
// cols x 64 co (acc[4][4]).  A window 6x66 pos x 32ch slice (25.3 KB),
// reg-prefetched at each of CC=4 slice boundaries (issue-early/write-late).
// B page 3kw x 128co x 64B dbuf (24.6 KB x2, T14).  LDS 74.5 KB -> 2/CU.
__global__ __launch_bounds__(512, 2) void k_conv3_mc(
    const ushort* __restrict__ in, ushort* __restrict__ out,
    const ushort* __restrict__ wbase, int wlstride,
    const float* __restrict__ bs0, const float* __restrict__ bb0,
    const float* __restrict__ bm0, const float* __restrict__ bv0, int d0)
{
    constexpr int AB = 6 * 66 * 64;              // 25344 B
    constexpr int PB = 3 * 128 * 64;             // 24576 B
    constexpr int SA = 4;
    constexpr int SB = 3;                        // 3*8192 == PB
    constexpr int NPH = 12;                      // 3 kh x 4 cc
    __shared__ __align__(16) char smem[AB + 2 * PB];
    char* As = smem;

    const int tid = threadIdx.x;
    const int lane = tid & 63, wid = tid >> 6;
    const int lr = lane & 15, kg = lane >> 4;
    const int wr = wid >> 1, coh = wid & 1;
    const int r0 = (int)blockIdx.x * 4;
    const int slot = blockIdx.z;
    const int l = (d0 + slot) / 49;

    int aoff[SA]; unsigned awr = 0, avalid = 0;
    #pragma unroll
    for (int i = 0; i < SA; ++i) {
        int lin = i * 8192 + tid * 16;
        bool wrk = lin < AB;
        int linc = wrk ? lin : 0;
        int pos = linc >> 6;
        int prow = (pos * 994) >> 16;            // /66 for pos<660
        int pcol = pos - prow * 66;
        int grow = r0 - 1 + prow, gcol = pcol - 1;
        bool ok = wrk && ((unsigned)grow < 48u) && ((unsigned)gcol < 64u);
        if (wrk) awr |= 1u << i;
        if (ok) avalid |= 1u << i;
        int growc = min(max(grow, 0), 47), gcolc = min(max(gcol, 0), 63);
        aoff[i] = (growc * 64 + gcolc) * 128 + ((linc & 63) >> 1);
    }
    int boff[SB];
    #pragma unroll
    for (int i = 0; i < SB; ++i) {
        int lin = i * 8192 + tid * 16;           // < PB always
        int rowidx = lin >> 6;                   // 0..383
        int tpg = rowidx >> 7, r = rowidx & 127; // kw, co
        boff[i] = (tpg * 128 + r) * 128 + ((lin & 63) >> 1);
    }

    const ushort* ib = in + (size_t)slot * 3072 * 128;
    const ushort* wl = wbase + (size_t)l * wlstride;
    const short8 z8 = {0, 0, 0, 0, 0, 0, 0, 0};

    short8 stgA[SA], stgB[SB];
    auto loadA = [&](int cc) {
        #pragma unroll
        for (int i = 0; i < SA; ++i) {
            if ((avalid >> i) & 1) stgA[i] = *(const short8*)(ib + aoff[i] + cc * 32);
            else stgA[i] = z8;
        }
    };
    auto writeA = [&]() {
        #pragma unroll
        for (int i = 0; i < SA; ++i) {
            int lin = i * 8192 + tid * 16;
            if ((awr >> i) & 1)
                *(short8*)(As + swz(lin)) = stgA[i];
        }
    };
    auto loadB = [&](int ps) {
        int pg = ps % 3, cc = ps / 3;
        const ushort* src = wl + pg * (3 * 128 * 128) + cc * 32;
        #pragma unroll
        for (int i = 0; i < SB; ++i)
            stgB[i] = *(const short8*)(src + boff[i]);
    };
    auto writeB = [&](int ps) {
        char* Bs = smem + AB + (ps & 1) * PB;
        #pragma unroll
        for (int i = 0; i < SB; ++i) {
            int lin = i * 8192 + tid * 16;
            *(short8*)(Bs + swz(lin)) = stgB[i];
        }
    };

    f32x4 acc[4][4];
    #pragma unroll
    for (int mf = 0; mf < 4; ++mf)
        #pragma unroll
        for (int nf = 0; nf < 4; ++nf)
            acc[mf][nf] = (f32x4){0.f, 0.f, 0.f, 0.f};

    loadA(0); loadB(0);
    writeA(); writeB(0);
    __syncthreads();

    #pragma unroll 1
    for (int ps = 0; ps < NPH; ++ps) {
        const int pg = ps % 3;                    // = kh
        const bool hasNext = (ps + 1 < NPH);
        const bool newA = (pg == 2) && hasNext;
        if (hasNext) loadB(ps + 1);               // T14: issue before compute
        if (newA) loadA(ps / 3 + 1);

        const char* Bs = smem + AB + (ps & 1) * PB;
        #pragma unroll
        for (int kw = 0; kw < 3; ++kw) {
            short8 a[4];
            #pragma unroll
            for (int mf = 0; mf < 4; ++mf) {
                int sp = (wr + pg) * 66 + mf * 16 + lr + kw;
                a[mf] = *(const short8*)(As + swz(sp * 64 + kg * 16));
            }
            #pragma unroll
            for (int nf = 0; nf < 4; ++nf) {
                int rb = kw * 128 + coh * 64 + nf * 16 + lr;
                short8 b = *(const short8*)(Bs + swz(rb * 64 + kg * 16));
                #pragma unroll
                for (int mf = 0; mf < 4; ++mf)
                    acc[mf][nf] = __builtin_amdgcn_mfma_f32_16x16x32_bf16(
                        a[mf], b, acc[mf][nf], 0, 0, 0);
            }
        }

        __syncthreads();
        if (hasNext) {
            writeB(ps + 1);
            if (newA) writeA();
            __syncthreads();
        }
    }

    const float* bs = bs0 + l * 128;
    const float* bb = bb0 + l * 128;
    const float* bm = bm0 + l * 128;
    const float* bv = bv0 + l * 128;
    ushort* ob = out + (size_t)slot * 3072 * 128;
    const int orow = r0 + wr;
    #pragma unroll
    for (int nf = 0; nf < 4; ++nf) {
        const int col = coh * 64 + nf * 16 + lr;
        const float inv = bs[col] * rsqrtf(bv[col] + EPSF);
        const float beta = bb[col] - bm[col] * inv;
        #pragma unroll
        for (int mf = 0; mf < 4; ++mf) {
            #pragma unroll
            for (int j = 0; j < 4; ++j) {
                int ocol = mf * 16 + kg * 4 + j;
                float y = fmaxf(fmaf(acc[mf][nf][j], inv, beta), 0.f);
                ob[((size_t)orow * 64 + ocol) * 128 + col] = f2bf(y);
            }
        }
    }
}

// ---------------- conv4: slim 2-blocks/CU stride-1 conv3x3 -----------------
template <int CIN, int COUT, int IH, int IW>
__global__ __launch_bounds__(512, 4) void k_conv_lds8s(
    const ushort* __restrict__ in, ushort* __restrict__ out,
    const ushort* __restrict__ wbase, int wlstride,
    const float* __restrict__ bs0, const float* __restrict__ bb0,
    const float* __restrict__ bm0, const float* __restrict__ bv0, int d0)
{
    constexpr int CCs = CIN / 32;                // 4
    constexpr int AB = 10 * 66 * 64;             // 42240 B
    constexpr int PB = 3 * 64 * 64;              // 12288 B
    constexpr int SA = 6, SB = 2;
    constexpr int NPH = 3 * CCs;                 // 12
    __shared__ __align__(16) char smem[AB + 2 * PB];
    char* As = smem;

    const int tid = threadIdx.x;
    const int lane = tid & 63, wid = tid >> 6;
    const int lr = lane & 15, kg = lane >> 4;
    const int r0 = (int)blockIdx.x * 8;
    const int co0 = (int)blockIdx.y * 64;
    const int slot = blockIdx.z;
    const int l = (d0 + slot) / 49;

    int aoff[SA]; unsigned awr = 0, avalid = 0;
    #pragma unroll
    for (int i = 0; i < SA; ++i) {
        int lin = i * 8192 + tid * 16;
        bool wr = lin < AB;
        int linc = wr ? lin : 0;
        int pos = linc >> 6;
        int prow = (pos * 994) >> 16;            // /66 for pos<660
        int pcol = pos - prow * 66;
        int grow = r0 - 1 + prow, gcol = pcol - 1;
        bool ok = wr && ((unsigned)grow < (unsigned)IH) && ((unsigned)gcol < (unsigned)IW);
        if (wr) awr |= 1u << i;
        if (ok) avalid |= 1u << i;
        int growc = min(max(grow, 0), IH - 1), gcolc = min(max(gcol, 0), IW - 1);
        aoff[i] = (growc * IW + gcolc) * CIN + ((linc & 63) >> 1);
    }
    int boff[SB]; unsigned bmask = 0;
    #pragma unroll
    for (int i = 0; i < SB; ++i) {
        int lin = i * 8192 + tid * 16;
        if (lin < PB) bmask |= 1u << i;
        int lc = min(lin, PB - 16);
        int rowidx = lc >> 6;                    // 0..191
        int tpg = rowidx >> 6, r = rowidx & 63;  // kw, co offset
        boff[i] = (tpg * COUT + co0 + r) * CIN + ((lc & 63) >> 1);
    }

    const ushort* ib = in + (size_t)slot * IH * IW * CIN;
    const ushort* wl = wbase + (size_t)l * wlstride;
    const short8 z8 = {0, 0, 0, 0, 0, 0, 0, 0};

    auto stageA = [&](int cc) {
        #pragma unroll
        for (int i = 0; i < SA; ++i) {
            int lin = i * 8192 + tid * 16;
            if ((awr >> i) & 1) {
                short8 v = z8;
                if ((avalid >> i) & 1)
                    v = *(const short8*)(ib + aoff[i] + cc * 32);
                *(short8*)(As + swz(lin)) = v;
            }
        }
    };
    short8 stgB[SB];
    auto loadB = [&](int ps) {
        int pg = ps % 3, cc = ps / 3;
        const ushort* src = wl + pg * (3 * COUT * CIN) + cc * 32;
        #pragma unroll
        for (int i = 0; i < SB; ++i)
            if ((bmask >> i) & 1) stgB[i] = *(const short8*)(src + boff[i]);
    };
    auto writeB = [&](int ps) {
        char* Bs = smem + AB + (ps & 1) * PB;
        #pragma unroll
        for (int i = 0; i < SB; ++i) {
            int lin = i * 8192 + tid * 16;
            if ((bmask >> i) & 1) *(short8*)(Bs + swz(lin)) = stgB[i];
        }
    };

    f32x4 acc[4][4];
    #pragma unroll
    for (int mf = 0; mf < 4; ++mf)
        #pragma unroll
        for (int nf = 0; nf < 4; ++nf)
            acc[mf][nf] = (f32x4){0.f, 0.f, 0.f, 0.f};

    stageA(0);
    loadB(0); writeB(0);
    __syncthreads();

    #pragma unroll 1
    for (int ps = 0; ps < NPH; ++ps) {
        const int pg = ps % 3;                    // = kh
        const bool hasNext = (ps + 1 < NPH);
        if (hasNext) loadB(ps + 1);               // T14: issue before compute

        const char* Bs = smem + AB + (ps & 1) * PB;
        #pragma unroll
        for (int kw = 0; kw < 3; ++kw) {
            short8 a[4];
            #pragma unroll
            for (int mf = 0; mf < 4; ++mf) {
                int sp = (wid + pg) * 66 + mf * 16 + lr + kw;
                a[mf] = *(const short8*)(As + swz(sp * 64 + kg * 16));
            }
            #pragma unroll
            for (int nf = 0; nf < 4; ++nf) {
                short8 b = *(const short8*)(Bs + swz((kw * 64 + nf * 16 + lr) * 64 + kg * 16));
                #pragma unroll
                for (int mf = 0; mf < 4; ++mf)
                    acc[mf][nf] = __builtin_amdgcn_mfma_f32_16x16x32_bf16(
                        a[mf], b, acc[mf][nf], 0, 0, 0);
            }
        }

        __syncthreads();
        if (hasNext) {
            writeB(ps + 1);
            if (pg == 2) stageA(ps / 3 + 1);      // synchronous A restage
            __syncthreads();
        }
    }

    const float* bs = bs0 + l * COUT;
    const float* bb = bb0 + l * COUT;
    const float* bm = bm0 + l * COUT;
    const float* bv = bv0 + l * COUT;
    ushort* ob = out + (size_t)slot * IH * IW * COUT;
    const int orow = r0 + wid;
    #pragma unroll
    for (int nf = 0; nf < 4; ++nf) {
        const int col = co0 + nf * 16 + lr;
        const float inv = bs[col] * rsqrtf(bv[col] + EPSF);
        const float beta = bb[col] - bm[col] * inv;
        #pragma unroll
        for (int mf = 0; mf < 4; ++mf) {
            #pragma unroll
            for (int j = 0; j < 4; ++j) {
                int ocol = mf * 16 + kg * 4 + j;
                float y = fmaxf(fmaf(acc[mf][nf][j], inv, beta), 0.f);
                ob[((size_t)orow * IW + ocol) * COUT + col] = f2bf(y);
            }
        }
    }
}

// ---------------- conv2: merged-co, single-buf B, async A (T14) ------------
__global__ __launch_bounds__(512, 2) void k_conv_s2_8(
    const ushort* __restrict__ in, ushort* __restrict__ out,
    const ushort* __restrict__ wbase, int wlstride,
    const float* __restrict__ bs0, const float* __restrict__ bb0,
    const float* __restrict__ bm0, const float* __restrict__ bv0, int d0)
{
    constexpr int AB = 9 * 66 * 64;              // 38016 B
    constexpr int PB = 3 * 128 * 64;             // 24576 B (single buffer)
    constexpr int SA = 5;
    constexpr int SB = 3;                        // 3*8192 == PB exactly
    constexpr int NPH = 9;                       // 3 cc x 3 kh
    __shared__ __align__(16) char smem[AB + PB];
    char* As = smem;

    const int tid = threadIdx.x;
    const int lane = tid & 63, wid = tid >> 6;
    const int lr = lane & 15, kg = lane >> 4;
    const int mw = wid >> 2;                     // 0..1 row-pair
    const int cw = wid & 3;                      // 0..3 co-group of 32
    const int bx = blockIdx.x;
    const int rt = bx >> 1, ct = bx & 1;
    const int r0 = rt * 4, oc0 = ct * 32;
    const int slot = blockIdx.z;
    const int l = (d0 + slot) / 49;

    int aoff[SA]; unsigned awr = 0, avalid = 0;
    #pragma unroll
    for (int i = 0; i < SA; ++i) {
        int lin = i * 8192 + tid * 16;
        bool wr = lin < AB;
        int linc = wr ? lin : 0;
        int pos = linc >> 6;
        int prow = (pos * 994) >> 16;            // /66 for pos<594
        int pcol = pos - prow * 66;
        int grow = 2 * r0 - 1 + prow, gcol = 2 * oc0 - 1 + pcol;
        bool ok = wr && ((unsigned)grow < 96u) && ((unsigned)gcol < 128u);
        if (wr) awr |= 1u << i;
        if (ok) avalid |= 1u << i;
        int growc = min(max(grow, 0), 95), gcolc = min(max(gcol, 0), 127);
        aoff[i] = (growc * 128 + gcolc) * 96 + ((linc & 63) >> 1);
    }
    int boff[SB];
    #pragma unroll
    for (int i = 0; i < SB; ++i) {
        int lin = i * 8192 + tid * 16;           // < PB always
        int rowidx = lin >> 6;                   // 0..383
        int tpg = rowidx >> 7, r = rowidx & 127; // kw, co
        boff[i] = (tpg * 128 + r) * 96 + ((lin & 63) >> 1);
    }

    const ushort* ib = in + (size_t)slot * 12288 * 96;
    const ushort* wl = wbase + (size_t)l * wlstride;
    const short8 z8 = {0, 0, 0, 0, 0, 0, 0, 0};

    short8 stgA[SA], stgB[SB];
    auto loadA = [&](int cc) {
        #pragma unroll
        for (int i = 0; i < SA; ++i) {
            if ((avalid >> i) & 1) stgA[i] = *(const short8*)(ib + aoff[i] + cc * 32);
            else stgA[i] = z8;
        }
    };
    auto writeA = [&]() {
        #pragma unroll
        for (int i = 0; i < SA; ++i) {
            int lin = i * 8192 + tid * 16;
            if ((awr >> i) & 1)
                *(short8*)(As + swz(lin)) = stgA[i];
        }
    };
    auto loadB = [&](int ps) {
        int pg = ps % 3, cc = ps / 3;
        const ushort* src = wl + pg * (3 * 128 * 96) + cc * 32;
        #pragma unroll
        for (int i = 0; i < SB; ++i)
            stgB[i] = *(const short8*)(src + boff[i]);
    };
    auto writeB = [&]() {
        char* Bs = smem + AB;
        #pragma unroll
        for (int i = 0; i < SB; ++i) {
            int lin = i * 8192 + tid * 16;
            *(short8*)(Bs + swz(lin)) = stgB[i];
        }
    };

    f32x4 acc[4][2];
    #pragma unroll
    for (int mf = 0; mf < 4; ++mf)
        #pragma unroll
        for (int nf = 0; nf < 2; ++nf)
            acc[mf][nf] = (f32x4){0.f, 0.f, 0.f, 0.f};

    loadA(0); loadB(0);
    writeA(); writeB();
    __syncthreads();

    #pragma unroll 1
    for (int ps = 0; ps < NPH; ++ps) {
        const int pg = ps % 3;                    // = kh
        const bool hasNext = (ps + 1 < NPH);
        const bool newA = (pg == 2) && hasNext;
        if (hasNext) loadB(ps + 1);               // T14: issue before compute
        if (newA) loadA(ps / 3 + 1);

        const char* Bs = smem + AB;
        #pragma unroll
        for (int kw = 0; kw < 3; ++kw) {
            short8 a[4];
            #pragma unroll
            for (int mf = 0; mf < 4; ++mf) {
                int pos = (2 * (mw * 2 + (mf >> 1)) + pg) * 66
                        + 2 * ((mf & 1) * 16 + lr) + kw;
                a[mf] = *(const short8*)(As + swz(pos * 64 + kg * 16));
            }
            #pragma unroll
            for (int nf = 0; nf < 2; ++nf) {
                int rb = kw * 128 + cw * 32 + nf * 16 + lr;
                short8 b = *(const short8*)(Bs + swz(rb * 64 + kg * 16));
                #pragma unroll
                for (int mf = 0; mf < 4; ++mf)
                    acc[mf][nf] = __builtin_amdgcn_mfma_f32_16x16x32_bf16(
                        a[mf], b, acc[mf][nf], 0, 0, 0);
            }
        }

        __syncthreads();
        if (hasNext) {
            writeB();
            if (newA) writeA();
            __syncthreads();
        }
    }

    const float* bs = bs0 + l * 128;
    const float* bb = bb0 + l * 128;
    const float* bm = bm0 + l * 128;
    const float* bv = bv0 + l * 128;
    ushort* ob = out + (size_t)slot * 3072 * 128;
    #pragma unroll
    for (int nf = 0; nf < 2; ++nf) {
        const int col = cw * 32 + nf * 16 + lr;
        const float inv = bs[col] * rsqrtf(bv[col] + EPSF);
        const float beta = bb[col] - bm[col] * inv;
        #pragma unroll
        for (int mf = 0; mf < 4; ++mf) {
            const int orow = r0 + mw * 2 + (mf >> 1);
            #pragma unroll
            for (int j = 0; j < 4; ++j) {
                int ocol = oc0 + (mf & 1) * 16 + kg * 4 + j;
                float y = fmaxf(fmaf(acc[mf][nf][j], inv, beta), 0.f);
                ob[((size_t)orow * 64 + ocol) * 128 + col] = f2bf(y);
            }
        }
    }
}

// ---------------- convT 4x4 s2: slim LDS, 2 blocks/CU (+BN+ReLU) -----------
__global__ __launch_bounds__(512, 4) void k_convt_lds(
    const ushort* __restrict__ in, ushort* __restrict__ out,
    const ushort* __restrict__ wbase,
    const float* __restrict__ bs0, const float* __restrict__ bb0,
    const float* __restrict__ bm0, const float* __restrict__ bv0, int d0)
{
    constexpr int AB = 10 * 66 * 64;             // 42240 B
    constexpr int PB = 4 * 32 * 64;              // 8192 B
    constexpr int SA = 6;
    __shared__ __align__(16) char smem[AB + 2 * PB];
    char* As = smem;

    const int tid = threadIdx.x;
    const int lane = tid & 63, wid = tid >> 6;
    const int lr = lane & 15, kg = lane >> 4;
    const int q0 = (int)blockIdx.x * 8;
    const int parity = blockIdx.y;
    const int ph = parity >> 1, pw = parity & 1;
    const int slot = blockIdx.z;
    const int l = (d0 + slot) / 49;

    int aoff[SA]; unsigned awr = 0, avalid = 0;
    #pragma unroll
    for (int i = 0; i < SA; ++i) {
        int lin = i * 8192 + tid * 16;
        bool wr = lin < AB;
        int linc = wr ? lin : 0;
        int pos = linc >> 6;
        int prow = (pos * 994) >> 16;            // /66 for pos<660
        int pcol = pos - prow * 66;
        int grow = q0 - 1 + prow, gcol = pcol - 1;
        bool ok = wr && ((unsigned)grow < 48u) && ((unsigned)gcol < 64u);
        if (wr) awr |= 1u << i;
        if (ok) avalid |= 1u << i;
        int growc = min(max(grow, 0), 47), gcolc = min(max(gcol, 0), 63);
        aoff[i] = (growc * 64 + gcolc) * 64 + ((linc & 63) >> 1);
    }
    int boffB;
    {
        int lin = tid * 16;
        int rowidx = lin >> 6;                   // 0..127
        int tap = rowidx >> 5, co = rowidx & 31;
        boffB = ((parity * 4 + tap) * 32 + co) * 64 + ((lin & 63) >> 1);
    }

    const ushort* ib = in + (size_t)slot * 3072 * 64;
    const ushort* wl = wbase + (size_t)l * (16 * 32 * 64);
    const short8 z8 = {0, 0, 0, 0, 0, 0, 0, 0};

    auto stageA = [&](int cc) {
        #pragma unroll
        for (int i = 0; i < SA; ++i) {
            int lin = i * 8192 + tid * 16;
            if ((awr >> i) & 1) {
                short8 v = z8;
                if ((avalid >> i) & 1)
                    v = *(const short8*)(ib + aoff[i] + cc * 32);
                *(short8*)(As + swz(lin)) = v;
            }
        }
    };
    short8 stgB;
    auto loadB = [&](int cc) {
        stgB = *(const short8*)(wl + boffB + cc * 32);
    };
    auto writeB = [&](int cc) {
        char* Bs = smem + AB + (cc & 1) * PB;
        *(short8*)(Bs + swz(tid * 16)) = stgB;
    };

    f32x4 acc[4][2];
    #pragma unroll
    for (int mf = 0; mf < 4; ++mf)
        #pragma unroll
        for (int nf = 0; nf < 2; ++nf)
            acc[mf][nf] = (f32x4){0.f, 0.f, 0.f, 0.f};

    stageA(0);
    loadB(0); writeB(0);
    __syncthreads();

    #pragma unroll 1
    for (int cc = 0; cc < 2; ++cc) {
        if (cc == 0) loadB(1);                   // T14: issue before compute
        const char* Bs = smem + AB + (cc & 1) * PB;
        #pragma unroll
        for (int a = 0; a < 2; ++a) {
            #pragma unroll
            for (int b2 = 0; b2 < 2; ++b2) {
                const int tap = a * 2 + b2;
                short8 av[4];
                #pragma unroll
                for (int mf = 0; mf < 4; ++mf) {
                    int pos = (wid + 1 + ph - a) * 66 + mf * 16 + lr + pw - b2 + 1;
                    av[mf] = *(const short8*)(As + swz(pos * 64 + kg * 16));
                }
                #pragma unroll
                for (int nf = 0; nf < 2; ++nf) {
                    short8 b = *(const short8*)(Bs
                        + swz((tap * 32 + nf * 16 + lr) * 64 + kg * 16));
                    #pragma unroll
                    for (int mf = 0; mf < 4; ++mf)
                        acc[mf][nf] = __builtin_amdgcn_mfma_f32_16x16x32_bf16(
                            av[mf], b, acc[mf][nf], 0, 0, 0);
                }
            }
        }
        __syncthreads();
        if (cc == 0) {
            writeB(1);
            stageA(1);                            // synchronous A restage
            __syncthreads();
        }
    }

    const float* bs = bs0 + l * 32;
    const float* bb = bb0 + l * 32;
    const float* bm = bm0 + l * 32;
    const float* bv = bv0 + l * 32;
    ushort* ob = out + (size_t)slot * 12288 * 32;
    const size_t rowb = (size_t)(2 * (q0 + wid) + ph) * 128;
    #pragma unroll
    for (int nf = 0; nf < 2; ++nf) {
        const int col = nf * 16 + lr;
        const float inv = bs[col] * rsqrtf(bv[col] + EPSF);
        const float beta = bb[col] - bm[col] * inv;
        #pragma unroll
        for (int mf = 0; mf < 4; ++mf) {
            #pragma unroll
            for (int j = 0; j < 4; ++j) {
                int r = mf * 16 + kg * 4 + j;
                float y = fmaxf(fmaf(acc[mf][nf][j], inv, beta), 0.f);
                ob[(rowb + 2 * r + pw) * 32 + col] = f2bf(y);
            }
        }
    }
}

// ---------------- conv6 (32->1) + bias, fp32 out ---------------------------
__global__ __launch_bounds__(256) void k_conv6(
    const ushort* __restrict__ x5, float* __restrict__ cost,
    const float* __restrict__ w0, const float* __restrict__ cb6, int d0)
{
    const int sp = blockIdx.x * 256 + threadIdx.x;
    const int slot = blockIdx.z;
    const int p = d0 + slot;
    const int l = p / 49;
    const float* w = w0 + l * 288;
    const int oh = sp >> 7, ow = sp & 127;
    float acc = 0.f;
    #pragma unroll
    for (int kh = 0; kh < 3; ++kh) {
        const int ih = oh - 1 + kh;
        if (ih < 0 || ih >= 96) continue;
        #pragma unroll
        for (int kw = 0; kw < 3; ++kw) {
            const int iw = ow - 1 + kw;
            if (iw < 0 || iw >= 128) continue;
            const ushort* q = x5 + ((size_t)slot * 12288 + ih * 128 + iw) * 32;
            const int tap = kh * 3 + kw;
            #pragma unroll
            for (int g = 0; g < 4; ++g) {
                uint4 v = *(const uint4*)(q + g * 8);
                const uint* vw = (const uint*)&v;
                #pragma unroll
                for (int t = 0; t < 4; ++t) {
                    int ci = g * 8 + t * 2;
                    acc = fmaf(bf2f((ushort)(vw[t] & 0xFFFF)), w[ci * 9 + tap], acc);
                    acc = fmaf(bf2f((ushort)(vw[t] >> 16)), w[(ci + 1) * 9 + tap], acc);
                }
            }
        }
    }
    cost[(size_t)p * 12288 + sp] = acc + cb6[l];
}

// ---------------- DAP ------------------------------------------------------
__global__ __launch_bounds__(256) void k_dap(
    const float* __restrict__ cost, const float* __restrict__ dw,
    float* __restrict__ out)
{
    const int sp = blockIdx.x * 256 + threadIdx.x;
    const int p = blockIdx.y;
    const float* dr = dw + p * 49;
    float acc = 0.f;
    #pragma unroll
    for (int q = 0; q < 49; ++q)
        acc = fmaf(dr[q], cost[(size_t)q * 12288 + sp], acc);
    out[(size_t)p * 12288 + sp] = acc;
}

// ---------------------------------------------------------------------------
extern "C" void kernel_launch(void* const* d_in, const int* in_sizes, int n_in,
                              void* d_out, int out_size, void* d_ws, size_t ws_size,
                              hipStream_t stream)
{
    const float* fm1_0 = (const float*)d_in[0];
    const float* fm2_0 = (const float*)d_in[1];
    const float* fm1_1 = (const float*)d_in[2];
    const float* fm2_1 = (const float*)d_in[3];
    const float* coords = (const float*)d_in[4];
    const float* cw1  = (const float*)d_in[5];
    const float* cw2  = (const float*)d_in[6];
    const float* cw3  = (const float*)d_in[7];
    const float* cw4  = (const float*)d_in[8];
    const float* ctw5 = (const float*)d_in[9];
    const float* cw6  = (const float*)d_in[10];
    const float* cb6  = (const float*)d_in[11];
    const float* bn[5][4];
    for (int j = 0; j < 5; ++j)
        for (int k = 0; k < 4; ++k)
            bn[j][k] = (const float*)d_in[12 + j * 4 + k];
    const float* dap = (const float*)d_in[32];
    float* out = (float*)d_out;

    // ---- workspace: bufA | bufB | xf1(2 lv) | weights | P1 | cost | f2t ----
    const size_t A_US = 393216;    // per-slot: max(x0s, x2, x4)
    const size_t B_US = 1179648;   // per-slot: max(x1, x3, x5)
    const size_t XF1 = 2 * 393216;
    const size_t W1 = 9 * 96 * 64, W2 = 9 * 128 * 96, W3 = 9 * 128 * 128;
    const size_t W4 = 9 * 64 * 128, W5 = 16 * 32 * 64;
    const size_t W_US = 2 * (W1 + W2 + W3 + W4 + W5);
    const size_t P1F = 2 * (size_t)48 * 512 * 48;      // floats, both levels
    const size_t COSTF = (size_t)98 * 12288;
    const size_t F2TF = 2 * (size_t)12288 * 32;        // floats, both levels

    int DC = 1;
    for (int cand : {98, 66, 49, 42, 33, 25, 17, 13, 9, 7, 5, 3, 2, 1}) {
        size_t need = (A_US + B_US) * (size_t)cand * 2 + (XF1 + W_US) * 2
                    + (P1F + COSTF + F2TF) * 4 + 4096;
        if (need <= ws_size) { DC = cand; break; }
    }

    ushort* bufA = (ushort*)d_ws;
    ushort* bufB = bufA + A_US * DC;
    ushort* xf1 = bufB + B_US * DC;
    ushort* wp = xf1 + XF1;
    ushort* wr1 = wp; wp += 2 * W1;
    ushort* wr2 = wp; wp += 2 * W2;
    ushort* wr3 = wp; wp += 2 * W3;
    ushort* wr4 = wp; wp += 2 * W4;
    ushort* wr5 = wp; wp += 2 * W5;
    float* P1 = (float*)wp;
    float* cost = P1 + P1F;
    float* f2t = cost + COSTF;

    for (int l = 0; l < 2; ++l) {
        k_repack_conv<<<dim3(216), 256, 0, stream>>>(cw1 + (size_t)l * W1, wr1 + l * W1, 96, 64);
        k_repack_conv<<<dim3(432), 256, 0, stream>>>(cw2 + (size_t)l * W2, wr2 + l * W2, 128, 96);
        k_repack_conv<<<dim3(576), 256, 0, stream>>>(cw3 + (size_t)l * W3, wr3 + l * W3, 128, 128);
        k_repack_conv<<<dim3(288), 256, 0, stream>>>(cw4 + (size_t)l * W4, wr4 + l * W4, 64, 128);
        k_repack_ct<<<dim3(128), 256, 0, stream>>>(ctw5 + (size_t)l * W5, wr5 + l * W5);
    }

    // ---- one-time: f2 NHWC transpose + P1 = f1 (x) W1[:, 0:32] ----
    k_transpose_f2<<<dim3(48, 1, 2), 256, 0, stream>>>(fm2_0, fm2_1, f2t);
    k_pack_f1<<<dim3(48, 1, 2), 256, 0, stream>>>(fm1_0, fm1_1, xf1);
    k_conv1<1><<<dim3(48, 1, 2), 512, 0, stream>>>(
        xf1, (ushort*)P1, wr1, nullptr,
        bn[0][0], bn[0][1], bn[0][2], bn[0][3], 0, 0);

    for (int d0 = 0; d0 < 98; d0 += DC) {
        const int ndd = min(DC, 98 - d0);
        k_sample_nhwc<<<dim3(48, 1, ndd), 256, 0, stream>>>(
            f2t, coords, bufA, d0);
        k_conv1<0><<<dim3(48, 1, ndd), 512, 0, stream>>>(
            bufA, bufB, wr1, P1,
            bn[0][0], bn[0][1], bn[0][2], bn[0][3], d0, 32);
        k_conv_s2_8<<<dim3(24, 1, ndd), 512, 0, stream>>>(bufB, bufA, wr2, (int)W2,
                bn[1][0], bn[1][1], bn[1][2], bn[1][3], d0);
        k_conv3_mc<<<dim3(12, 1, ndd), 512, 0, stream>>>(bufA, bufB, wr3, (int)W3,
                bn[2][0], bn[2][1], bn[2][2], bn[2][3], d0);
        k_conv_lds8s<128, 64, 48, 64>
            <<<dim3(6, 1, ndd), 512, 0, stream>>>(bufB, bufA, wr4, (int)W4,
                bn[3][0], bn[3][1], bn[3][2], bn[3][3], d0);
        k_convt_lds<<<dim3(6, 4, ndd), 512, 0, stream>>>(bufA, bufB, wr5,
                bn[4][0], bn[4][1], bn[4][2], bn[4][3], d0);
        k_conv6<<<dim3(48, 1, ndd), 256, 0, stream>>>(
            bufB, cost, cw6, cb6, d0);
    }
    for (int l = 0; l < 2; ++l)
        k_dap<<<dim3(48, 49), 256, 0, stream>>>(
            cost + (size_t)l * 49 * 12288, dap + (size_t)l * 49 * 49,
            out + (size_t)l * 49 * 12288);
}

// Round 20
// 708.949 us; speedup vs baseline: 1.0964x; 1.0121x over previous
//
#include <hip/hip_runtime.h>

#define EPSF 1e-5f

typedef __attribute__((ext_vector_type(8))) short short8;
typedef __attribute__((ext_vector_type(4))) float f32x4;

__device__ __forceinline__ ushort f2bf(float x) {
    union { float f; unsigned u; } c; c.f = x;
    unsigned r = c.u + 0x7FFF + ((c.u >> 16) & 1);   // RNE
    return (ushort)(r >> 16);
}
__device__ __forceinline__ float bf2f(ushort b) {
    union { unsigned u; float f; } c; c.u = ((unsigned)b) << 16;
    return c.f;
}
// Uniform LDS swizzle: involution on the FULL linear byte address, applied on
// both write and read everywhere (rule #21).
__device__ __forceinline__ int swz(int a) {
    return a ^ (((a >> 7) & 7) << 4);
}

// ---------------------------------------------------------------------------
// Geometry: B=1, C=32, H=96, W=128, L=2, N=7 (49 displacements/level).
// blockIdx.z spans merged (level,d) pairs p = d0 + z, p in [0,98).
// Activations NHWC bf16, unpadded:
//   x0s [slot][12288][32] (sampled f2 half)   x1 [slot][12288][96]
//   x2,x3 [slot][3072][128]   x4 [slot][3072][64]  x5 [slot][12288][32]
// P1 [l][bx48][tid512][mf4][nf3][4] f32 = f1 (x) W1[:, 0:32] raw partials.
// F2T [l][12288][32] f32 = f2 transposed to NHWC.
// Weights repacked [l][tap][COUT][CIN] bf16; ctw5 [l][parity][tap][32][64].
// ---------------------------------------------------------------------------

__global__ __launch_bounds__(256) void k_repack_conv(
    const float* __restrict__ src, ushort* __restrict__ dst, int CO, int CI)
{
    int idx = blockIdx.x * 256 + threadIdx.x;
    if (idx >= CO * CI * 9) return;
    int co = idx / (CI * 9);
    int rem = idx % (CI * 9);
    int ci = rem / 9, tap = rem % 9;
    dst[((size_t)tap * CO + co) * CI + ci] = f2bf(src[idx]);
}

// ctw5 [64][32][4][4] fp32 -> [parity(4)][tap(4)][32co][64ci] bf16
__global__ __launch_bounds__(256) void k_repack_ct(
    const float* __restrict__ src, ushort* __restrict__ dst)
{
    int idx = blockIdx.x * 256 + threadIdx.x;
    if (idx >= 4 * 4 * 32 * 64) return;
    int ci = idx & 63;
    int t = idx >> 6;
    int co = t & 31; t >>= 5;
    int tap = t & 3;
    int parity = t >> 2;
    int ph = parity >> 1, pw = parity & 1;
    int a = tap >> 1, b = tap & 1;
    int kh = ((ph + 1) & 1) + 2 * a;
    int kw = ((pw + 1) & 1) + 2 * b;
    dst[idx] = f2bf(src[((ci * 32 + co) * 4 + kh) * 4 + kw]);
}

// ---------------- pack f1 planar fp32 -> xf1 [l][12288][32] bf16 -----------
__global__ __launch_bounds__(256) void k_pack_f1(
    const float* __restrict__ f1_0, const float* __restrict__ f1_1,
    ushort* __restrict__ xf1)
{
    const int sp = blockIdx.x * 256 + threadIdx.x;
    const int l = blockIdx.z;
    const float* f1 = l ? f1_1 : f1_0;
    ushort* dst = xf1 + (size_t)l * 393216 + (size_t)sp * 32;
    #pragma unroll
    for (int g = 0; g < 4; ++g) {
        uint4 pk;
        uint* pw_ = (uint*)&pk;
        #pragma unroll
        for (int q = 0; q < 4; ++q) {
            int c = g * 8 + q * 2;
            pw_[q] = (uint)f2bf(f1[(size_t)c * 12288 + sp])
                   | ((uint)f2bf(f1[(size_t)(c + 1) * 12288 + sp]) << 16);
        }
        *(uint4*)(dst + g * 8) = pk;
    }
}

// ---------------- transpose f2 planar fp32 -> f2t [l][12288][32] f32 -------
__global__ __launch_bounds__(256) void k_transpose_f2(
    const float* __restrict__ f2_0, const float* __restrict__ f2_1,
    float* __restrict__ f2t)
{
    const int sp = blockIdx.x * 256 + threadIdx.x;
    const int l = blockIdx.z;
    const float* f2 = l ? f2_1 : f2_0;
    float* dst = f2t + (size_t)l * 393216 + (size_t)sp * 32;
    #pragma unroll
    for (int c = 0; c < 32; ++c)
        dst[c] = f2[(size_t)c * 12288 + sp];
}

// ---------------- sample f2t (NHWC f32) -> x0s [slot][12288][32] -----------
__global__ __launch_bounds__(256) void k_sample_nhwc(
    const float* __restrict__ f2t, const float* __restrict__ coords,
    ushort* __restrict__ x0s, int d0)
{
    const int HW = 12288;
    const int sp = blockIdx.x * 256 + threadIdx.x;
    const int slot = blockIdx.z;
    const int p = d0 + slot;
    const int l = p / 49;
    const int d = p - l * 49;
    const int du = d / 7, dv = d % 7;
    const float inv_scale = l ? 0.5f : 1.0f;
    const float* ft = f2t + (size_t)l * 393216;

    float cx = coords[sp] * inv_scale + (float)(du - 3);
    float cy = coords[HW + sp] * inv_scale + (float)(dv - 3);
    float xf = floorf(cx), yf = floorf(cy);
    float wx = cx - xf, wy = cy - yf;
    int xi = (int)xf, yi = (int)yf;
    float vx0 = (xf >= 0.f && xf <= 127.f) ? 1.f : 0.f;
    float vx1 = (xf + 1.f >= 0.f && xf + 1.f <= 127.f) ? 1.f : 0.f;
    float vy0 = (yf >= 0.f && yf <= 95.f) ? 1.f : 0.f;
    float vy1 = (yf + 1.f >= 0.f && yf + 1.f <= 95.f) ? 1.f : 0.f;
    int x0i = min(max(xi, 0), 127), x1i = min(max(xi + 1, 0), 127);
    int y0i = min(max(yi, 0), 95),  y1i = min(max(yi + 1, 0), 95);
    float w00 = (1.f - wx) * (1.f - wy) * vx0 * vy0;
    float w01 = wx * (1.f - wy) * vx1 * vy0;
    float w10 = (1.f - wx) * wy * vx0 * vy1;
    float w11 = wx * wy * vx1 * vy1;
    const float* r00 = ft + (size_t)(y0i * 128 + x0i) * 32;
    const float* r01 = ft + (size_t)(y0i * 128 + x1i) * 32;
    const float* r10 = ft + (size_t)(y1i * 128 + x0i) * 32;
    const float* r11 = ft + (size_t)(y1i * 128 + x1i) * 32;

    uint w[16];
    #pragma unroll
    for (int q = 0; q < 8; ++q) {
        float4 a = *(const float4*)(r00 + q * 4);
        float4 b = *(const float4*)(r01 + q * 4);
        float4 c = *(const float4*)(r10 + q * 4);
        float4 e = *(const float4*)(r11 + q * 4);
        float s0 = w00 * a.x + w01 * b.x + w10 * c.x + w11 * e.x;
        float s1 = w00 * a.y + w01 * b.y + w10 * c.y + w11 * e.y;
        float s2 = w00 * a.z + w01 * b.z + w10 * c.z + w11 * e.z;
        float s3 = w00 * a.w + w01 * b.w + w10 * c.w + w11 * e.w;
        w[2 * q]     = (uint)f2bf(s0) | ((uint)f2bf(s1) << 16);
        w[2 * q + 1] = (uint)f2bf(s2) | ((uint)f2bf(s3) << 16);
    }
    ushort* dst = x0s + ((size_t)slot * HW + sp) * 32;
    #pragma unroll
    for (int g = 0; g < 4; ++g)
        *(uint4*)(dst + g * 8) = *(uint4*)(w + g * 4);
}

// ---------------- conv1: merged-co, 8 waves = 4 rows x 2 co-halves ---------
template <int EPI>
__global__ __launch_bounds__(512, 2) void k_conv1(
    const ushort* __restrict__ in,     // EPI0: x0s[slot]; EPI1: xf1[l]
    ushort* __restrict__ out,          // EPI0: x1; EPI1: (float*)P1 base
    const ushort* __restrict__ wbase,  // wr1 [l][9][96][64]
    const float* __restrict__ p1,      // EPI0: P1 base
    const float* __restrict__ bs0, const float* __restrict__ bb0,
    const float* __restrict__ bm0, const float* __restrict__ bv0,
    int d0, int koff)
{
    constexpr int AB = 6 * 66 * 64;              // 25344 B
    constexpr int PB = 3 * 96 * 64;              // 18432 B
    constexpr int SA = 4;
    constexpr int SB = 3;
    __shared__ __align__(16) char smem[AB + 2 * PB];
    char* As = smem;

    const int tid = threadIdx.x;
    const int lane = tid & 63, wid = tid >> 6;
    const int lr = lane & 15, kg = lane >> 4;
    const int bx = blockIdx.x;
    const int rt = bx >> 1, ct = bx & 1;
    const int r0 = rt * 4, c0 = ct * 64;
    const int wr = wid >> 1, coh = wid & 1;
    const int slot = blockIdx.z;
    const int l = EPI ? slot : (d0 + slot) / 49;

    const ushort* ib = in + (size_t)slot * 12288 * 32;
    const ushort* wl = wbase + (size_t)l * (9 * 96 * 64);
    const short8 z8 = {0, 0, 0, 0, 0, 0, 0, 0};

    // ---- A stage (once) ----
    #pragma unroll
    for (int i = 0; i < SA; ++i) {
        int lin = i * 8192 + tid * 16;
        if (lin < AB) {
            int pos = lin >> 6;
            int prow = (pos * 994) >> 16;        // /66 for pos<660
            int pcol = pos - prow * 66;
            int grow = r0 - 1 + prow, gcol = c0 - 1 + pcol;
            bool ok = ((unsigned)grow < 96u) && ((unsigned)gcol < 128u);
            short8 v = z8;
            if (ok) v = *(const short8*)(ib + (grow * 128 + gcol) * 32 + ((lin & 63) >> 1));
            *(short8*)(As + swz(lin)) = v;
        }
    }

    // ---- B staging tables ----
    int boff[SB]; unsigned bmask = 0;
    #pragma unroll
    for (int i = 0; i < SB; ++i) {
        int lin = i * 8192 + tid * 16;
        if (lin < PB) bmask |= 1u << i;
        int lc = min(lin, PB - 16);
        int rowidx = lc >> 6;                    // 0..287
        int tpg = rowidx / 96;                   // kw
        int r = rowidx - tpg * 96;               // co
        boff[i] = (tpg * 96 + r) * 64 + koff + ((lc & 63) >> 1);
    }
    short8 stgB[SB];
    auto loadB = [&](int pg) {
        const ushort* src = wl + pg * (3 * 96 * 64);
        #pragma unroll
        for (int i = 0; i < SB; ++i)
            if ((bmask >> i) & 1) stgB[i] = *(const short8*)(src + boff[i]);
    };
    auto writeB = [&](int pg) {
        char* Bs = smem + AB + (pg & 1) * PB;
        #pragma unroll
        for (int i = 0; i < SB; ++i) {
            int lin = i * 8192 + tid * 16;
            if ((bmask >> i) & 1) *(short8*)(Bs + swz(lin)) = stgB[i];
        }
    };

    // ---- accumulators ----
    f32x4 acc[4][3];
    if constexpr (EPI == 0) {
        const float* pl = p1 + (size_t)l * 1179648
                        + ((size_t)(bx * 512 + tid)) * 48;
        #pragma unroll
        for (int mf = 0; mf < 4; ++mf)
            #pragma unroll
            for (int nf = 0; nf < 3; ++nf)
                acc[mf][nf] = *(const f32x4*)(pl + (mf * 3 + nf) * 4);
    } else {
        #pragma unroll
        for (int mf = 0; mf < 4; ++mf)
            #pragma unroll
            for (int nf = 0; nf < 3; ++nf)
                acc[mf][nf] = (f32x4){0.f, 0.f, 0.f, 0.f};
    }

    loadB(0);
    writeB(0);
    __syncthreads();

    #pragma unroll
    for (int ps = 0; ps < 3; ++ps) {             // ps = kh
        if (ps < 2) loadB(ps + 1);               // T14: issue before compute
        const char* Bs = smem + AB + (ps & 1) * PB;
        #pragma unroll
        for (int kw = 0; kw < 3; ++kw) {
            short8 a[4];
            #pragma unroll
            for (int mf = 0; mf < 4; ++mf) {
                int sp = (wr + ps) * 66 + mf * 16 + lr + kw;
                a[mf] = *(const short8*)(As + swz(sp * 64 + kg * 16));
            }
            #pragma unroll
            for (int nf = 0; nf < 3; ++nf) {
                int rb = kw * 96 + coh * 48 + nf * 16 + lr;
                short8 b = *(const short8*)(Bs + swz(rb * 64 + kg * 16));
                #pragma unroll
                for (int mf = 0; mf < 4; ++mf)
                    acc[mf][nf] = __builtin_amdgcn_mfma_f32_16x16x32_bf16(
                        a[mf], b, acc[mf][nf], 0, 0, 0);
            }
        }
        __syncthreads();
        if (ps < 2) { writeB(ps + 1); __syncthreads(); }
    }

    if constexpr (EPI == 1) {
        float* of = (float*)out + (size_t)l * 1179648
                  + ((size_t)(bx * 512 + tid)) * 48;
        #pragma unroll
        for (int mf = 0; mf < 4; ++mf)
            #pragma unroll
            for (int nf = 0; nf < 3; ++nf)
                *(f32x4*)(of + (mf * 3 + nf) * 4) = acc[mf][nf];
    } else {
        const float* bs = bs0 + l * 96;
        const float* bb = bb0 + l * 96;
        const float* bm = bm0 + l * 96;
        const float* bv = bv0 + l * 96;
        ushort* ob = out + (size_t)slot * 12288 * 96;
        const int orow = r0 + wr;
        #pragma unroll
        for (int nf = 0; nf < 3; ++nf) {
            const int col = coh * 48 + nf * 16 + lr;
            const float inv = bs[col] * rsqrtf(bv[col] + EPSF);
            const float beta = bb[col] - bm[col] * inv;
            #pragma unroll
            for (int mf = 0; mf < 4; ++mf) {
                #pragma unroll
                for (int j = 0; j < 4; ++j) {
                    int ocol = c0 + mf * 16 + kg * 4 + j;
                    float yv = fmaxf(fmaf(acc[mf][nf][j], inv, beta), 0.f);
                    ob[((size_t)orow * 128 + ocol) * 96 + col] = f2bf(yv);
                }
            }
        }
    }
}

// ---------------- conv3/conv4: slim 2-blocks/CU stride-1 conv3x3 -----------
template <int CIN, int COUT, int IH, int IW>
__global__ __launch_bounds__(512, 4) void k_conv_lds8s(
    const ushort* __restrict__ in, ushort* __restrict__ out,
    const ushort* __restrict__ wbase, int wlstride,
    const float* __restrict__ bs0, const float* __restrict__ bb0,
    const float* __restrict__ bm0, const float* __restrict__ bv0, int d0)
{
    constexpr int CCs = CIN / 32;                // 4
    constexpr int AB = 10 * 66 * 64;             // 42240 B
    constexpr int PB = 3 * 64 * 64;              // 12288 B
    constexpr int SA = 6, SB = 2;
    constexpr int NPH = 3 * CCs;                 // 12
    __shared__ __align__(16) char smem[AB + 2 * PB];
    char* As = smem;

    const int tid = threadIdx.x;
    const int lane = tid & 63, wid = tid >> 6;
    const int lr = lane & 15, kg = lane >> 4;
    const int r0 = (int)blockIdx.x * 8;
    const int co0 = (int)blockIdx.y * 64;
    const int slot = blockIdx.z;
    const int l = (d0 + slot) / 49;

    int aoff[SA]; unsigned awr = 0, avalid = 0;
    #pragma unroll
    for (int i = 0; i < SA; ++i) {
        int lin = i * 8192 + tid * 16;
        bool wr = lin < AB;
        int linc = wr ? lin : 0;
        int pos = linc >> 6;
        int prow = (pos * 994) >> 16;            // /66 for pos<660
        int pcol = pos - prow * 66;
        int grow = r0 - 1 + prow, gcol = pcol - 1;
        bool ok = wr && ((unsigned)grow < (unsigned)IH) && ((unsigned)gcol < (unsigned)IW);
        if (wr) awr |= 1u << i;
        if (ok) avalid |= 1u << i;
        int growc = min(max(grow, 0), IH - 1), gcolc = min(max(gcol, 0), IW - 1);
        aoff[i] = (growc * IW + gcolc) * CIN + ((linc & 63) >> 1);
    }
    int boff[SB]; unsigned bmask = 0;
    #pragma unroll
    for (int i = 0; i < SB; ++i) {
        int lin = i * 8192 + tid * 16;
        if (lin < PB) bmask |= 1u << i;
        int lc = min(lin, PB - 16);
        int rowidx = lc >> 6;                    // 0..191
        int tpg = rowidx >> 6, r = rowidx & 63;  // kw, co offset
        boff[i] = (tpg * COUT + co0 + r) * CIN + ((lc & 63) >> 1);
    }

    const ushort* ib = in + (size_t)slot * IH * IW * CIN;
    const ushort* wl = wbase + (size_t)l * wlstride;
    const short8 z8 = {0, 0, 0, 0, 0, 0, 0, 0};

    auto stageA = [&](int cc) {
        #pragma unroll
        for (int i = 0; i < SA; ++i) {
            int lin = i * 8192 + tid * 16;
            if ((awr >> i) & 1) {
                short8 v = z8;
                if ((avalid >> i) & 1)
                    v = *(const short8*)(ib + aoff[i] + cc * 32);
                *(short8*)(As + swz(lin)) = v;
            }
        }
    };
    short8 stgB[SB];
    auto loadB = [&](int ps) {
        int pg = ps % 3, cc = ps / 3;
        const ushort* src = wl + pg * (3 * COUT * CIN) + cc * 32;
        #pragma unroll
        for (int i = 0; i < SB; ++i)
            if ((bmask >> i) & 1) stgB[i] = *(const short8*)(src + boff[i]);
    };
    auto writeB = [&](int ps) {
        char* Bs = smem + AB + (ps & 1) * PB;
        #pragma unroll
        for (int i = 0; i < SB; ++i) {
            int lin = i * 8192 + tid * 16;
            if ((bmask >> i) & 1) *(short8*)(Bs + swz(lin)) = stgB[i];
        }
    };

    f32x4 acc[4][4];
    #pragma unroll
    for (int mf = 0; mf < 4; ++mf)
        #pragma unroll
        for (int nf = 0; nf < 4; ++nf)
            acc[mf][nf] = (f32x4){0.f, 0.f, 0.f, 0.f};

    stageA(0);
    loadB(0); writeB(0);
    __syncthreads();

    #pragma unroll 1
    for (int ps = 0; ps < NPH; ++ps) {
        const int pg = ps % 3;                    // = kh
        const bool hasNext = (ps + 1 < NPH);
        if (hasNext) loadB(ps + 1);               // T14: issue before compute

        const char* Bs = smem + AB + (ps & 1) * PB;
        #pragma unroll
        for (int kw = 0; kw < 3; ++kw) {
            short8 a[4];
            #pragma unroll
            for (int mf = 0; mf < 4; ++mf) {
                int sp = (wid + pg) * 66 + mf * 16 + lr + kw;
                a[mf] = *(const short8*)(As + swz(sp * 64 + kg * 16));
            }
            #pragma unroll
            for (int nf = 0; nf < 4; ++nf) {
                short8 b = *(const short8*)(Bs + swz((kw * 64 + nf * 16 + lr) * 64 + kg * 16));
                #pragma unroll
                for (int mf = 0; mf < 4; ++mf)
                    acc[mf][nf] = __builtin_amdgcn_mfma_f32_16x16x32_bf16(
                        a[mf], b, acc[mf][nf], 0, 0, 0);
            }
        }

        __syncthreads();
        if (hasNext) {
            writeB(ps + 1);
            if (pg == 2) stageA(ps / 3 + 1);      // synchronous A restage
            __syncthreads();
        }
    }

    const float* bs = bs0 + l * COUT;
    const float* bb = bb0 + l * COUT;
    const float* bm = bm0 + l * COUT;
    const float* bv = bv0 + l * COUT;
    ushort* ob = out + (size_t)slot * IH * IW * COUT;
    const int orow = r0 + wid;
    #pragma unroll
    for (int nf = 0; nf < 4; ++nf) {
        const int col = co0 + nf * 16 + lr;
        const float inv = bs[col] * rsqrtf(bv[col] + EPSF);
        const float beta = bb[col] - bm[col] * inv;
        #pragma unroll
        for (int mf = 0; mf < 4; ++mf) {
            #pragma unroll
            for (int j = 0; j < 4; ++j) {
                int ocol = mf * 16 + kg * 4 + j;
                float y = fmaxf(fmaf(acc[mf][nf][j], inv, beta), 0.f);
                ob[((size_t)orow * IW + ocol) * COUT + col] = f2bf(y);
            }
        }
    }
}

// ---------------- conv2: merged-co, single-buf B, async A (T14) ------------
__global__ __launch_bounds__(512, 2) void k_conv_s2_8(
    const ushort* __restrict__ in, ushort* __restrict__ out,
    const ushort* __restrict__ wbase, int wlstride,
    const float* __restrict__ bs0, const float* __restrict__ bb0,
    const float* __restrict__ bm0, const float* __restrict__ bv0, int d0)
{
    constexpr int AB = 9 * 66 * 64;              // 38016 B
    constexpr int PB = 3 * 128 * 64;             // 24576 B (single buffer)
    constexpr int SA = 5;
    constexpr int SB = 3;                        // 3*8192 == PB exactly
    constexpr int NPH = 9;                       // 3 cc x 3 kh
    __shared__ __align__(16) char smem[AB + PB];
    char* As = smem;

    const int tid = threadIdx.x;
    const int lane = tid & 63, wid = tid >> 6;
    const int lr = lane & 15, kg = lane >> 4;
    const int mw = wid >> 2;                     // 0..1 row-pair
    const int cw = wid & 3;                      // 0..3 co-group of 32
    const int bx = blockIdx.x;
    const int rt = bx >> 1, ct = bx & 1;
    const int r0 = rt * 4, oc0 = ct * 32;
    const int slot = blockIdx.z;
    const int l = (d0 + slot) / 49;

    int aoff[SA]; unsigned awr = 0, avalid = 0;
    #pragma unroll
    for (int i = 0; i < SA; ++i) {
        int lin = i * 8192 + tid * 16;
        bool wr = lin < AB;
        int linc = wr ? lin : 0;
        int pos = linc >> 6;
        int prow = (pos * 994) >> 16;            // /66 for pos<594
        int pcol = pos - prow * 66;
        int grow = 2 * r0 - 1 + prow, gcol = 2 * oc0 - 1 + pcol;
        bool ok = wr && ((unsigned)grow < 96u) && ((unsigned)gcol < 128u);
        if (wr) awr |= 1u << i;
        if (ok) avalid |= 1u << i;
        int growc = min(max(grow, 0), 95), gcolc = min(max(gcol, 0), 127);
        aoff[i] = (growc * 128 + gcolc) * 96 + ((linc & 63) >> 1);
    }
    int boff[SB];
    #pragma unroll
    for (int i = 0; i < SB; ++i) {
        int lin = i * 8192 + tid * 16;           // < PB always
        int rowidx = lin >> 6;                   // 0..383
        int tpg = rowidx >> 7, r = rowidx & 127; // kw, co
        boff[i] = (tpg * 128 + r) * 96 + ((lin & 63) >> 1);
    }

    const ushort* ib = in + (size_t)slot * 12288 * 96;
    const ushort* wl = wbase + (size_t)l * wlstride;
    const short8 z8 = {0, 0, 0, 0, 0, 0, 0, 0};

    short8 stgA[SA], stgB[SB];
    auto loadA = [&](int cc) {
        #pragma unroll
        for (int i = 0; i < SA; ++i) {
            if ((avalid >> i) & 1) stgA[i] = *(const short8*)(ib + aoff[i] + cc * 32);
            else stgA[i] = z8;
        }
    };
    auto writeA = [&]() {
        #pragma unroll
        for (int i = 0; i < SA; ++i) {
            int lin = i * 8192 + tid * 16;
            if ((awr >> i) & 1)
                *(short8*)(As + swz(lin)) = stgA[i];
        }
    };
    auto loadB = [&](int ps) {
        int pg = ps % 3, cc = ps / 3;
        const ushort* src = wl + pg * (3 * 128 * 96) + cc * 32;
        #pragma unroll
        for (int i = 0; i < SB; ++i)
            stgB[i] = *(const short8*)(src + boff[i]);
    };
    auto writeB = [&]() {
        char* Bs = smem + AB;
        #pragma unroll
        for (int i = 0; i < SB; ++i) {
            int lin = i * 8192 + tid * 16;
            *(short8*)(Bs + swz(lin)) = stgB[i];
        }
    };

    f32x4 acc[4][2];
    #pragma unroll
    for (int mf = 0; mf < 4; ++mf)
        #pragma unroll
        for (int nf = 0; nf < 2; ++nf)
            acc[mf][nf] = (f32x4){0.f, 0.f, 0.f, 0.f};

    loadA(0); loadB(0);
    writeA(); writeB();
    __syncthreads();

    #pragma unroll 1
    for (int ps = 0; ps < NPH; ++ps) {
        const int pg = ps % 3;                    // = kh
        const bool hasNext = (ps + 1 < NPH);
        const bool newA = (pg == 2) && hasNext;
        if (hasNext) loadB(ps + 1);               // T14: issue before compute
        if (newA) loadA(ps / 3 + 1);

        const char* Bs = smem + AB;
        #pragma unroll
        for (int kw = 0; kw < 3; ++kw) {
            short8 a[4];
            #pragma unroll
            for (int mf = 0; mf < 4; ++mf) {
                int pos = (2 * (mw * 2 + (mf >> 1)) + pg) * 66
                        + 2 * ((mf & 1) * 16 + lr) + kw;
                a[mf] = *(const short8*)(As + swz(pos * 64 + kg * 16));
            }
            #pragma unroll
            for (int nf = 0; nf < 2; ++nf) {
                int rb = kw * 128 + cw * 32 + nf * 16 + lr;
                short8 b = *(const short8*)(Bs + swz(rb * 64 + kg * 16));
                #pragma unroll
                for (int mf = 0; mf < 4; ++mf)
                    acc[mf][nf] = __builtin_amdgcn_mfma_f32_16x16x32_bf16(
                        a[mf], b, acc[mf][nf], 0, 0, 0);
            }
        }

        __syncthreads();
        if (hasNext) {
            writeB();
            if (newA) writeA();
            __syncthreads();
        }
    }

    const float* bs = bs0 + l * 128;
    const float* bb = bb0 + l * 128;
    const float* bm = bm0 + l * 128;
    const float* bv = bv0 + l * 128;
    ushort* ob = out + (size_t)slot * 3072 * 128;
    #pragma unroll
    for (int nf = 0; nf < 2; ++nf) {
        const int col = cw * 32 + nf * 16 + lr;
        const float inv = bs[col] * rsqrtf(bv[col] + EPSF);
        const float beta = bb[col] - bm[col] * inv;
        #pragma unroll
        for (int mf = 0; mf < 4; ++mf) {
            const int orow = r0 + mw * 2 + (mf >> 1);
            #pragma unroll
            for (int j = 0; j < 4; ++j) {
                int ocol = oc0 + (mf & 1) * 16 + kg * 4 + j;
                float y = fmaxf(fmaf(acc[mf][nf][j], inv, beta), 0.f);
                ob[((size_t)orow * 64 + ocol) * 128 + col] = f2bf(y);
            }
        }
    }
}

// ---------------- convT 4x4 s2: slim LDS, 2 blocks/CU (+BN+ReLU) -----------
__global__ __launch_bounds__(512, 4) void k_convt_lds(
    const ushort* __restrict__ in, ushort* __restrict__ out,
    const ushort* __restrict__ wbase,
    const float* __restrict__ bs0, const float* __restrict__ bb0,
    const float* __restrict__ bm0, const float* __restrict__ bv0, int d0)
{
    constexpr int AB = 10 * 66 * 64;             // 42240 B
    constexpr int PB = 4 * 32 * 64;              // 8192 B
    constexpr int SA = 6;
    __shared__ __align__(16) char smem[AB + 2 * PB];
    char* As = smem;

    const int tid = threadIdx.x;
    const int lane = tid & 63, wid = tid >> 6;
    const int lr = lane & 15, kg = lane >> 4;
    const int q0 = (int)blockIdx.x * 8;
    const int parity = blockIdx.y;
    const int ph = parity >> 1, pw = parity & 1;
    const int slot = blockIdx.z;
    const int l = (d0 + slot) / 49;

    int aoff[SA]; unsigned awr = 0, avalid = 0;
    #pragma unroll
    for (int i = 0; i < SA; ++i) {
        int lin = i * 8192 + tid * 16;
        bool wr = lin < AB;
        int linc = wr ? lin : 0;
        int pos = linc >> 6;
        int prow = (pos * 994) >> 16;            // /66 for pos<660
        int pcol = pos - prow * 66;
        int grow = q0 - 1 + prow, gcol = pcol - 1;
        bool ok = wr && ((unsigned)grow < 48u) && ((unsigned)gcol < 64u);
        if (wr) awr |= 1u << i;
        if (ok) avalid |= 1u << i;
        int growc = min(max(grow, 0), 47), gcolc = min(max(gcol, 0), 63);
        aoff[i] = (growc * 64 + gcolc) * 64 + ((linc & 63) >> 1);
    }
    int boffB;
    {
        int lin = tid * 16;
        int rowidx = lin >> 6;                   // 0..127
        int tap = rowidx >> 5, co = rowidx & 31;
        boffB = ((parity * 4 + tap) * 32 + co) * 64 + ((lin & 63) >> 1);
    }

    const ushort* ib = in + (size_t)slot * 3072 * 64;
    const ushort* wl = wbase + (size_t)l * (16 * 32 * 64);
    const short8 z8 = {0, 0, 0, 0, 0, 0, 0, 0};

    auto stageA = [&](int cc) {
        #pragma unroll
        for (int i = 0; i < SA; ++i) {
            int lin = i * 8192 + tid * 16;
            if ((awr >> i) & 1) {
                short8 v = z8;
                if ((avalid >> i) & 1)
                    v = *(const short8*)(ib + aoff[i] + cc * 32);
                *(short8*)(As + swz(lin)) = v;
            }
        }
    };
    short8 stgB;
    auto loadB = [&](int cc) {
        stgB = *(const short8*)(wl + boffB + cc * 32);
    };
    auto writeB = [&](int cc) {
        char* Bs = smem + AB + (cc & 1) * PB;
        *(short8*)(Bs + swz(tid * 16)) = stgB;
    };

    f32x4 acc[4][2];
    #pragma unroll
    for (int mf = 0; mf < 4; ++mf)
        #pragma unroll
        for (int nf = 0; nf < 2; ++nf)
            acc[mf][nf] = (f32x4){0.f, 0.f, 0.f, 0.f};

    stageA(0);
    loadB(0); writeB(0);
    __syncthreads();

    #pragma unroll 1
    for (int cc = 0; cc < 2; ++cc) {
        if (cc == 0) loadB(1);                   // T14: issue before compute
        const char* Bs = smem + AB + (cc & 1) * PB;
        #pragma unroll
        for (int a = 0; a < 2; ++a) {
            #pragma unroll
            for (int b2 = 0; b2 < 2; ++b2) {
                const int tap = a * 2 + b2;
                short8 av[4];
                #pragma unroll
                for (int mf = 0; mf < 4; ++mf) {
                    int pos = (wid + 1 + ph - a) * 66 + mf * 16 + lr + pw - b2 + 1;
                    av[mf] = *(const short8*)(As + swz(pos * 64 + kg * 16));
                }
                #pragma unroll
                for (int nf = 0; nf < 2; ++nf) {
                    short8 b = *(const short8*)(Bs
                        + swz((tap * 32 + nf * 16 + lr) * 64 + kg * 16));
                    #pragma unroll
                    for (int mf = 0; mf < 4; ++mf)
                        acc[mf][nf] = __builtin_amdgcn_mfma_f32_16x16x32_bf16(
                            av[mf], b, acc[mf][nf], 0, 0, 0);
                }
            }
        }
        __syncthreads();
        if (cc == 0) {
            writeB(1);
            stageA(1);                            // synchronous A restage
            __syncthreads();
        }
    }

    const float* bs = bs0 + l * 32;
    const float* bb = bb0 + l * 32;
    const float* bm = bm0 + l * 32;
    const float* bv = bv0 + l * 32;
    ushort* ob = out + (size_t)slot * 12288 * 32;
    const size_t rowb = (size_t)(2 * (q0 + wid) + ph) * 128;
    #pragma unroll
    for (int nf = 0; nf < 2; ++nf) {
        const int col = nf * 16 + lr;
        const float inv = bs[col] * rsqrtf(bv[col] + EPSF);
        const float beta = bb[col] - bm[col] * inv;
        #pragma unroll
        for (int mf = 0; mf < 4; ++mf) {
            #pragma unroll
            for (int j = 0; j < 4; ++j) {
                int r = mf * 16 + kg * 4 + j;
                float y = fmaxf(fmaf(acc[mf][nf][j], inv, beta), 0.f);
                ob[(rowb + 2 * r + pw) * 32 + col] = f2bf(y);
            }
        }
    }
}

// ---------------- conv6 (32->1) + bias, fp32 out ---------------------------
__global__ __launch_bounds__(256) void k_conv6(
    const ushort* __restrict__ x5, float* __restrict__ cost,
    const float* __restrict__ w0, const float* __restrict__ cb6, int d0)
{
    const int sp = blockIdx.x * 256 + threadIdx.x;
    const int slot = blockIdx.z;
    const int p = d0 + slot;
    const int l = p / 49;
    const float* w = w0 + l * 288;
    const int oh = sp >> 7, ow = sp & 127;
    float acc = 0.f;
    #pragma unroll
    for (int kh = 0; kh < 3; ++kh) {
        const int ih = oh - 1 + kh;
        if (ih < 0 || ih >= 96) continue;
        #pragma unroll
        for (int kw = 0; kw < 3; ++kw) {
            const int iw = ow - 1 + kw;
            if (iw < 0 || iw >= 128) continue;
            const ushort* q = x5 + ((size_t)slot * 12288 + ih * 128 + iw) * 32;
            const int tap = kh * 3 + kw;
            #pragma unroll
            for (int g = 0; g < 4; ++g) {
                uint4 v = *(const uint4*)(q + g * 8);
                const uint* vw = (const uint*)&v;
                #pragma unroll
                for (int t = 0; t < 4; ++t) {
                    int ci = g * 8 + t * 2;
                    acc = fmaf(bf2f((ushort)(vw[t] & 0xFFFF)), w[ci * 9 + tap], acc);
                    acc = fmaf(bf2f((ushort)(vw[t] >> 16)), w[(ci + 1) * 9 + tap], acc);
                }
            }
        }
    }
    cost[(size_t)p * 12288 + sp] = acc + cb6[l];
}

// ---------------- DAP ------------------------------------------------------
__global__ __launch_bounds__(256) void k_dap(
    const float* __restrict__ cost, const float* __restrict__ dw,
    float* __restrict__ out)
{
    const int sp = blockIdx.x * 256 + threadIdx.x;
    const int p = blockIdx.y;
    const float* dr = dw + p * 49;
    float acc = 0.f;
    #pragma unroll
    for (int q = 0; q < 49; ++q)
        acc = fmaf(dr[q], cost[(size_t)q * 12288 + sp], acc);
    out[(size_t)p * 12288 + sp] = acc;
}

// ---------------------------------------------------------------------------
extern "C" void kernel_launch(void* const* d_in, const int* in_sizes, int n_in,
                              void* d_out, int out_size, void* d_ws, size_t ws_size,
                              hipStream_t stream)
{
    const float* fm1_0 = (const float*)d_in[0];
    const float* fm2_0 = (const float*)d_in[1];
    const float* fm1_1 = (const float*)d_in[2];
    const float* fm2_1 = (const float*)d_in[3];
    const float* coords = (const float*)d_in[4];
    const float* cw1  = (const float*)d_in[5];
    const float* cw2  = (const float*)d_in[6];
    const float* cw3  = (const float*)d_in[7];
    const float* cw4  = (const float*)d_in[8];
    const float* ctw5 = (const float*)d_in[9];
    const float* cw6  = (const float*)d_in[10];
    const float* cb6  = (const float*)d_in[11];
    const float* bn[5][4];
    for (int j = 0; j < 5; ++j)
        for (int k = 0; k < 4; ++k)
            bn[j][k] = (const float*)d_in[12 + j * 4 + k];
    const float* dap = (const float*)d_in[32];
    float* out = (float*)d_out;

    // ---- workspace: bufA | bufB | xf1(2 lv) | weights | P1 | cost | f2t ----
    const size_t A_US = 393216;    // per-slot: max(x0s, x2, x4)
    const size_t B_US = 1179648;   // per-slot: max(x1, x3, x5)
    const size_t XF1 = 2 * 393216;
    const size_t W1 = 9 * 96 * 64, W2 = 9 * 128 * 96, W3 = 9 * 128 * 128;
    const size_t W4 = 9 * 64 * 128, W5 = 16 * 32 * 64;
    const size_t W_US = 2 * (W1 + W2 + W3 + W4 + W5);
    const size_t P1F = 2 * (size_t)48 * 512 * 48;      // floats, both levels
    const size_t COSTF = (size_t)98 * 12288;
    const size_t F2TF = 2 * (size_t)12288 * 32;        // floats, both levels

    int DC = 1;
    for (int cand : {98, 66, 49, 42, 33, 25, 17, 13, 9, 7, 5, 3, 2, 1}) {
        size_t need = (A_US + B_US) * (size_t)cand * 2 + (XF1 + W_US) * 2
                    + (P1F + COSTF + F2TF) * 4 + 4096;
        if (need <= ws_size) { DC = cand; break; }
    }

    ushort* bufA = (ushort*)d_ws;
    ushort* bufB = bufA + A_US * DC;
    ushort* xf1 = bufB + B_US * DC;
    ushort* wp = xf1 + XF1;
    ushort* wr1 = wp; wp += 2 * W1;
    ushort* wr2 = wp; wp += 2 * W2;
    ushort* wr3 = wp; wp += 2 * W3;
    ushort* wr4 = wp; wp += 2 * W4;
    ushort* wr5 = wp; wp += 2 * W5;
    float* P1 = (float*)wp;
    float* cost = P1 + P1F;
    float* f2t = cost + COSTF;

    for (int l = 0; l < 2; ++l) {
        k_repack_conv<<<dim3(216), 256, 0, stream>>>(cw1 + (size_t)l * W1, wr1 + l * W1, 96, 64);
        k_repack_conv<<<dim3(432), 256, 0, stream>>>(cw2 + (size_t)l * W2, wr2 + l * W2, 128, 96);
        k_repack_conv<<<dim3(576), 256, 0, stream>>>(cw3 + (size_t)l * W3, wr3 + l * W3, 128, 128);
        k_repack_conv<<<dim3(288), 256, 0, stream>>>(cw4 + (size_t)l * W4, wr4 + l * W4, 64, 128);
        k_repack_ct<<<dim3(128), 256, 0, stream>>>(ctw5 + (size_t)l * W5, wr5 + l * W5);
    }

    // ---- one-time: f2 NHWC transpose + P1 = f1 (x) W1[:, 0:32] ----
    k_transpose_f2<<<dim3(48, 1, 2), 256, 0, stream>>>(fm2_0, fm2_1, f2t);
    k_pack_f1<<<dim3(48, 1, 2), 256, 0, stream>>>(fm1_0, fm1_1, xf1);
    k_conv1<1><<<dim3(48, 1, 2), 512, 0, stream>>>(
        xf1, (ushort*)P1, wr1, nullptr,
        bn[0][0], bn[0][1], bn[0][2], bn[0][3], 0, 0);

    for (int d0 = 0; d0 < 98; d0 += DC) {
        const int ndd = min(DC, 98 - d0);
        k_sample_nhwc<<<dim3(48, 1, ndd), 256, 0, stream>>>(
            f2t, coords, bufA, d0);
        k_conv1<0><<<dim3(48, 1, ndd), 512, 0, stream>>>(
            bufA, bufB, wr1, P1,
            bn[0][0], bn[0][1], bn[0][2], bn[0][3], d0, 32);
        k_conv_s2_8<<<dim3(24, 1, ndd), 512, 0, stream>>>(bufB, bufA, wr2, (int)W2,
                bn[1][0], bn[1][1], bn[1][2], bn[1][3], d0);
        k_conv_lds8s<128, 128, 48, 64>
            <<<dim3(6, 2, ndd), 512, 0, stream>>>(bufA, bufB, wr3, (int)W3,
                bn[2][0], bn[2][1], bn[2][2], bn[2][3], d0);
        k_conv_lds8s<128, 64, 48, 64>
            <<<dim3(6, 1, ndd), 512, 0, stream>>>(bufB, bufA, wr4, (int)W4,
                bn[3][0], bn[3][1], bn[3][2], bn[3][3], d0);
        k_convt_lds<<<dim3(6, 4, ndd), 512, 0, stream>>>(bufA, bufB, wr5,
                bn[4][0], bn[4][1], bn[4][2], bn[4][3], d0);
        k_conv6<<<dim3(48, 1, ndd), 256, 0, stream>>>(
            bufB, cost, cw6, cb6, d0);
    }
    for (int l = 0; l < 2; ++l)
        k_dap<<<dim3(48, 49), 256, 0, stream>>>(
            cost + (size_t)l * 49 * 12288, dap + (size_t)l * 49 * 49,
            out + (size_t)l * 49 * 12288);
}